// Round 22
// baseline (362.429 us; speedup 1.0000x reference)
//
#include <hip/hip_runtime.h>
#include <math.h>

// ---------------- problem constants ----------------
constexpr int M1 = 2000, M2 = 400, BS = 8;
constexpr int AT = M1 + M2;            // 2400
constexpr int NN = BS * AT;            // 19200 nodes
constexpr int E1 = 60000, E2 = 20000, E3 = 20000;
constexpr int ET = E1 + E2 + E3;       // 100000
constexpr int H = 64, F = 64, NG = 50, L = 4, C = 4;
constexpr float CUTOFF = 10.0f;
constexpr float LOG2F_ = 0.6931471805599453f;

constexpr float SMEAR_STEP = 10.0f / 49.0f;
constexpr float SMEAR_COEFF = -12.005f;
constexpr float PI_OVER_CUT = 0.31415926535897932f; // pi/10

constexpr int NBLK = (ET + 255) / 256;

// Edge-MLP lerp table: packed bf16 pair {v_p, v_{p+1}} per (slice,p,feature).
constexpr int NT = 512;
constexpr float DSCALE = (float)(NT - 1) / CUTOFF;   // 51.1

// GEMM tiling
constexpr int TILE_M = 32;
constexpr int MT = NN / TILE_M;        // 600 i-groups (AT/4)

// Candidate dst sets (gather): g0 -> [0,M1), g1 -> [M1,AT), g2 -> [0,M1)
constexpr int NB0 = M1 / 4;            // 500 blocks
constexpr int NB1 = M2 / 4;            // 100
constexpr int NB2 = M1 / 4;            // 500
constexpr int NBTOT = NB0 + NB1 + NB2; // 1100

// Candidate SRC tiles (lin1): g0,g1 srcs < M1 (500 tiles); g2 srcs >= M1 (100)
constexpr int LT0 = M1 / 4;            // 500
constexpr int LT1 = M1 / 4;            // 500
constexpr int LT2 = M2 / 4;            // 100
constexpr int LTOT = LT0 + LT1 + LT2;  // 1100

// ---------------- workspace layout (bytes) ----------------
constexpr size_t O_HA    = 0;                            // hA [NN,64] f32 (4.9MB)
constexpr size_t O_HB    = O_HA  + (size_t)NN * 64 * 4;  // hB [NN,64] f32 (4.9MB)
constexpr size_t O_XG    = O_HB  + (size_t)NN * 64 * 4;  // xg [3][AT][64][8] BF16 (7.4MB)
constexpr size_t O_DG    = O_XG  + (size_t)3 * AT * 512 * 2; // dg [3,NN,64] f32 (tabF aliases)
constexpr size_t O_TAB2  = O_DG  + (size_t)3 * NN * 64 * 4;  // tab2 [48,NT,64] uint (6.3MB)
constexpr size_t O_EDATA = O_TAB2 + (size_t)48 * NT * 64 * 8; // edata [ET] int4
constexpr size_t O_INT   = O_EDATA + (size_t)ET * 16;
constexpr int I_DEG  = 0;      // [3*AT] zeroed
constexpr int I_CUR  = 7200;   // [3*AT] zeroed
constexpr int I_ZEND = 14400;
constexpr int I_BASE = 14400;  // [3*(AT+1)] = 7203
constexpr int I_PERM = 21616;  // [4400] candidate dsts sorted by degree (per g)
constexpr int I_CV   = 26016;  // [12*64] float cv rows (bit-reinterpreted storage)

__device__ inline float sspf(float x) {
    return fmaxf(x, 0.0f) + log1pf(expf(-fabsf(x))) - LOG2F_;
}
__device__ inline float sspf_fast(float x) {
    float t = __expf(-fabsf(x));
    return fmaxf(x, 0.0f) + __logf(1.0f + t) - LOG2F_;
}

// fp32 -> bf16 with round-to-nearest-even (bit manipulation, 4 VALU)
__device__ inline unsigned int bf16rn(float x) {
    unsigned int u = __float_as_uint(x);
    u = (u + 0x7FFFu + ((u >> 16) & 1u)) >> 16;
    return u & 0xFFFFu;
}

__device__ inline int graph_off(int g) { return g == 0 ? 0 : (g == 1 ? E1 : E1 + E2); }

__device__ inline void edge_decode(int idx, int& g, int& e,
                                   const int* ei1, const int* ei2, const int* ei3,
                                   const int* c1, const int* c2, const int* c3,
                                   const int*& ei, const int*& cl) {
    if (idx < E1)            { g = 0; e = idx;           ei = ei1; cl = c1; }
    else if (idx < E1 + E2)  { g = 1; e = idx - E1;      ei = ei2; cl = c2; }
    else                     { g = 2; e = idx - E1 - E2; ei = ei3; cl = c3; }
}

// ---------------- setup kernels ----------------
__global__ void k_init_h(const int* __restrict__ sites, const int* __restrict__ sites_p,
                         const float* __restrict__ emb_w, const float* __restrict__ emb_p_w,
                         float* __restrict__ h) {
    int idx = blockIdx.x * blockDim.x + threadIdx.x;
    if (idx >= NN * 64) return;
    int f = idx & 63;
    int n = idx >> 6;
    int b = n / AT;
    int i = n - b * AT;
    float v;
    if (i < M1) v = emb_w[sites[b * M1 + i] * H + f];
    else        v = emb_p_w[sites_p[b * M2 + (i - M1)] * H + f];
    h[idx] = v;
}

__global__ void k_count(const int* __restrict__ ei1, const int* __restrict__ ei2,
                        const int* __restrict__ ei3, const int* __restrict__ c1,
                        const int* __restrict__ c2, const int* __restrict__ c3,
                        int* __restrict__ deg) {
    int idx = blockIdx.x * blockDim.x + threadIdx.x;
    if (idx >= ET) return;
    int g, e; const int* ei; const int* cl;
    edge_decode(idx, g, e, ei1, ei2, ei3, c1, c2, c3, ei, cl);
    atomicAdd(&deg[g * AT + ei[2 * e + 1]], 1);
}

__global__ void k_scan(const int* __restrict__ deg, int* __restrict__ base) {
    const int T = 256, CH = 10;
    int t = threadIdx.x;
    __shared__ int lsum[T];
    int g = blockIdx.x;
    int loc[CH];
    int s = 0;
    #pragma unroll
    for (int i = 0; i < CH; i++) {
        int idx = t * CH + i;
        int v = (idx < AT) ? deg[g * AT + idx] : 0;
        loc[i] = s;
        s += v;
    }
    lsum[t] = s;
    __syncthreads();
    for (int off = 1; off < T; off <<= 1) {
        int v = 0;
        if (t >= off) v = lsum[t - off];
        __syncthreads();
        lsum[t] += v;
        __syncthreads();
    }
    int tb = lsum[t] - s;
    #pragma unroll
    for (int i = 0; i < CH; i++) {
        int idx = t * CH + i;
        if (idx < AT) base[g * (AT + 1) + idx] = tb + loc[i];
    }
    if (t == T - 1) base[g * (AT + 1) + AT] = lsum[T - 1];
}

// Counting sort (ascending degree) of each graph's CANDIDATE dsts only.
__global__ void k_sort(const int* __restrict__ deg, int* __restrict__ perm) {
    __shared__ int hist[256];
    __shared__ int cur[256];
    int g = blockIdx.x, t = threadIdx.x;
    int off   = (g == 1) ? M1 : 0;
    int cnt   = (g == 1) ? M2 : M1;
    int pbase = (g == 0) ? 0 : ((g == 1) ? M1 : (M1 + M2));
    hist[t] = 0;
    __syncthreads();
    for (int i = t; i < cnt; i += 256)
        atomicAdd(&hist[min(deg[g * AT + off + i], 255)], 1);
    __syncthreads();
    if (t == 0) {
        int run = 0;
        for (int k = 0; k < 256; k++) { cur[k] = run; run += hist[k]; }
    }
    __syncthreads();
    for (int i = t; i < cnt; i += 256) {
        int pos = atomicAdd(&cur[min(deg[g * AT + off + i], 255)], 1);
        perm[pbase + pos] = off + i;
    }
}

__global__ void k_fill(const int* __restrict__ ei1, const int* __restrict__ ei2,
                       const int* __restrict__ ei3, const int* __restrict__ c1,
                       const int* __restrict__ c2, const int* __restrict__ c3,
                       const float* __restrict__ ew1, const float* __restrict__ ew2,
                       const float* __restrict__ ew3,
                       const int* __restrict__ base, int* __restrict__ cur,
                       int4* __restrict__ edata) {
    int idx = blockIdx.x * blockDim.x + threadIdx.x;
    if (idx >= ET) return;
    int g, e; const int* ei; const int* cl;
    edge_decode(idx, g, e, ei1, ei2, ei3, c1, c2, c3, ei, cl);
    const float* ew = (g == 0) ? ew1 : (g == 1 ? ew2 : ew3);
    int dst = ei[2 * e + 1];
    int src = ei[2 * e];
    int p = base[g * (AT + 1) + dst] + atomicAdd(&cur[g * AT + dst], 1);
    float t = ew[e] * DSCALE;
    int i0 = min((int)t, NT - 2);
    float fr = t - (float)i0;
    int cb = cl[e] * (L * NT) + i0;
    edata[graph_off(g) + p] = make_int4(src, cb, __float_as_int(fr), 0);
}

// Per-(l,g) constant row cv = ssp(cb2)@bw + bb, computed ONCE (grid 12 x 64).
__global__ void k_cv(const float* __restrict__ conv_b2,
                     const float* __restrict__ blk_w,
                     const float* __restrict__ blk_b,
                     float* __restrict__ cvbuf) {
    int lane = threadIdx.x;      // 64
    int s = blockIdx.x;          // l*3+g, 0..11
    float sl = sspf(conv_b2[s * 64 + lane]);
    const float* bw = blk_w + (size_t)s * 4096;
    float a = blk_b[s * 64 + lane];
    #pragma unroll 8
    for (int k = 0; k < 64; k++)
        a = fmaf(__shfl(sl, k), bw[k * 64 + lane], a);
    cvbuf[s * 64 + lane] = a;
}

// ---------------- edge-MLP table build ----------------
// Stage 1: fp32 values (plain coalesced layout) into scratch (aliases dg).
__global__ __launch_bounds__(256) void k_table(
    const float* __restrict__ mlp_w1, const float* __restrict__ mlp_b1,
    const float* __restrict__ mlp_w2, const float* __restrict__ mlp_b2,
    float* __restrict__ tabF) {
    const int lane = threadIdx.x & 63;
    int w = blockIdx.x * 4 + (threadIdx.x >> 6);
    int s = w >> 9;
    int p = w & (NT - 1);
    int l = s % L;
    int gc = s / L;
    int c = gc % C;
    int g = gc / C;
    float d = (float)p * (CUTOFF / (float)(NT - 1));

    size_t wb = (size_t)((l * 3 + g) * C + c);
    const float* w1 = mlp_w1 + wb * NG * F;
    const float* w2 = mlp_w2 + wb * F * F;
    float w1c[NG], w2c[F];
    #pragma unroll
    for (int k = 0; k < NG; k++) w1c[k] = w1[k * F + lane];
    #pragma unroll
    for (int k = 0; k < F; k++) w2c[k] = w2[k * F + lane];
    float b1c = mlp_b1[wb * F + lane];
    float b2c = mlp_b2[wb * F + lane];

    float dd = d - (float)lane * SMEAR_STEP;
    float av = (lane < NG) ? __expf(SMEAR_COEFF * dd * dd) : 0.0f;
    float acc = b1c;
    #pragma unroll
    for (int k = 0; k < NG; k++) acc = fmaf(__shfl(av, k), w1c[k], acc);
    float t = sspf_fast(acc);
    float acc2 = b2c;
    #pragma unroll
    for (int j = 0; j < F; j++) acc2 = fmaf(__shfl(t, j), w2c[j], acc2);
    float ccut = 0.5f * (__cosf(d * PI_OVER_CUT) + 1.0f);
    tabF[((size_t)s * NT + p) * 64 + lane] = acc2 * ccut;
}

// Stage 2: pack {bf16(v_p), bf16(v_{p+1})} into one dword per entry.
__global__ void k_pack(const float* __restrict__ tabF,
                       unsigned int* __restrict__ tab2) {
    int idx = blockIdx.x * 256 + threadIdx.x;   // 48*NT*64 entries
    int pc = idx & (NT * 64 - 1);               // position within slice
    int nxt = (pc < (NT - 1) * 64) ? idx + 64 : idx;  // p=NT-1 never sampled
    unsigned int lo = bf16rn(tabF[idx]);
    unsigned int hi = bf16rn(tabF[nxt]);
    tab2[idx] = lo | (hi << 16);
}

// ---------------- LDS-tiled GEMM machinery ----------------
__device__ inline void fma4(float acc[4], float a, const float4 b) {
    acc[0] = fmaf(a, b.x, acc[0]);
    acc[1] = fmaf(a, b.y, acc[1]);
    acc[2] = fmaf(a, b.z, acc[2]);
    acc[3] = fmaf(a, b.w, acc[3]);
}

__device__ inline void stage_B(const float* __restrict__ gB, float (*Bs)[68], int t) {
    #pragma unroll
    for (int i = 0; i < 4; i++) {
        int v = t + i * 256;
        int r = v >> 4, c4 = (v & 15) * 4;
        *(float4*)&Bs[r][c4] = *(const float4*)(gB + (size_t)r * 64 + c4);
    }
}
__device__ inline void gemm_tile(const float (*As)[68], const float (*Bs)[68],
                                 int r0, int c0, float acc0[4], float acc1[4]) {
    #pragma unroll 4
    for (int k0 = 0; k0 < 64; k0 += 4) {
        float4 a0 = *(const float4*)&As[r0][k0];
        float4 a1 = *(const float4*)&As[r0 + 1][k0];
        float4 b0 = *(const float4*)&Bs[k0][c0];
        float4 b1 = *(const float4*)&Bs[k0 + 1][c0];
        float4 b2 = *(const float4*)&Bs[k0 + 2][c0];
        float4 b3 = *(const float4*)&Bs[k0 + 3][c0];
        fma4(acc0, a0.x, b0); fma4(acc0, a0.y, b1);
        fma4(acc0, a0.z, b2); fma4(acc0, a0.w, b3);
        fma4(acc1, a1.x, b0); fma4(acc1, a1.y, b1);
        fma4(acc1, a1.z, b2); fma4(acc1, a1.w, b3);
    }
}

// Transpose-pack As[(k*8+b)][c] (f32) -> xg[((g*AT+i0+k)*64+c)*8 + b] (bf16),
// one coalesced 16B uint4 per thread.
__device__ inline void xg_transpose_store(const float (*T)[68],
                                          unsigned short* __restrict__ xg,
                                          int g, int i0, int t) {
    int k = t >> 6, c = t & 63;
    unsigned int w0 = bf16rn(T[k * 8 + 0][c]) | (bf16rn(T[k * 8 + 1][c]) << 16);
    unsigned int w1 = bf16rn(T[k * 8 + 2][c]) | (bf16rn(T[k * 8 + 3][c]) << 16);
    unsigned int w2 = bf16rn(T[k * 8 + 4][c]) | (bf16rn(T[k * 8 + 5][c]) << 16);
    unsigned int w3 = bf16rn(T[k * 8 + 6][c]) | (bf16rn(T[k * 8 + 7][c]) << 16);
    unsigned short* out = xg + (((size_t)g * AT + i0 + k) * 64 + c) * 8;
    *(uint4*)out = make_uint4(w0, w1, w2, w3);
}

// lin1 candidate-tile mapping: g0,g1 need src tiles igrp<500; g2 needs >=500.
__device__ inline void lin1_map(int bid, int& g, int& igrp) {
    if (bid < LT0)            { g = 0; igrp = bid; }
    else if (bid < LT0 + LT1) { g = 1; igrp = bid - LT0; }
    else                      { g = 2; igrp = LT0 + (bid - LT0 - LT1); }
}

// xg[g] = h @ conv_w1[0,g]; grid LTOT (candidate src tiles only)
__global__ __launch_bounds__(256) void k_lin1t(
    const float* __restrict__ h, const float* __restrict__ conv_w1,
    unsigned short* __restrict__ xg, int l) {
    __shared__ float As[TILE_M][68];
    __shared__ float Bs[64][68];
    int t = threadIdx.x;
    int g, igrp;
    lin1_map(blockIdx.x, g, igrp);
    int i0 = igrp * 4;
    #pragma unroll
    for (int it = 0; it < 2; it++) {
        int v = t + it * 256;
        int r = v >> 4, c4 = (v & 15) * 4;
        int n = (r & 7) * AT + i0 + (r >> 3);
        *(float4*)&As[r][c4] = *(const float4*)(h + (size_t)n * 64 + c4);
    }
    stage_B(conv_w1 + (size_t)(l * 3 + g) * 4096, Bs, t);
    __syncthreads();
    int cg = t & 15, rg = t >> 4;
    int c0 = cg * 4, r0 = rg * 2;
    float acc0[4] = {0, 0, 0, 0}, acc1[4] = {0, 0, 0, 0};
    gemm_tile(As, Bs, r0, c0, acc0, acc1);
    __syncthreads();
    *(float4*)&As[r0][c0]     = make_float4(acc0[0], acc0[1], acc0[2], acc0[3]);
    *(float4*)&As[r0 + 1][c0] = make_float4(acc1[0], acc1[1], acc1[2], acc1[3]);
    __syncthreads();
    xg_transpose_store(As, xg, g, i0, t);
}

// ---------------- FUSED aggregation + node GEMMs ----------------
// Grid NBTOT=1100, LPT order. Gather: lane = feature c. Per edge:
// 3 broadcast shfl + 1 dword (packed bf16 table pair) + 1 dwordx4
// (8 bf16 batches of feature c) + lerp + 8 FMA. BOTH weight matrices
// staged during the gather (43.5KB LDS -> 3 blocks/CU; R13/R14 showed
// 3-vs-6 blocks is perf-neutral here) -> no mid-kernel L2 stall.
__global__ __launch_bounds__(256) void k_aggl(
    const int4* __restrict__ edata, const int* __restrict__ base,
    const int* __restrict__ perm,
    const unsigned short* __restrict__ xg, const unsigned int* __restrict__ tab2,
    const float* __restrict__ conv_w2, const float* __restrict__ conv_b2,
    const float* __restrict__ blk_w, const float* __restrict__ blk_b,
    float* __restrict__ dg, int l) {
    __shared__ float As[TILE_M][68];
    __shared__ float Bs[64][68];
    __shared__ float B2[64][68];
    int t = threadIdx.x;
    const int lane = t & 63;
    const int wv = t >> 6;
    int bid = blockIdx.x;
    int g, grp, nbg, pbase;
    if (bid < NB0)            { g = 0; grp = bid;             nbg = NB0; pbase = 0; }
    else if (bid < NB0 + NB1) { g = 1; grp = bid - NB0;       nbg = NB1; pbase = M1; }
    else                      { g = 2; grp = bid - NB0 - NB1; nbg = NB2; pbase = M1 + M2; }
    int gi = nbg - 1 - grp;               // heavy groups first (LPT)
    int dst = perm[pbase + gi * 4 + wv];
    size_t pb = (size_t)(l * 3 + g);
    stage_B(conv_w2 + pb * 4096, Bs, t);  // both staged under the gather
    stage_B(blk_w + pb * 4096, B2, t);

    const int4* ed = edata + graph_off(g);
    int s = base[g * (AT + 1) + dst];
    int e = base[g * (AT + 1) + dst + 1];
    const unsigned int* tg = tab2 + ((size_t)g * C * L * NT + (size_t)l * NT) * 64;
    const unsigned short* xgg = xg + (size_t)g * AT * 512;
    float acc[8];
    #pragma unroll
    for (int j = 0; j < 8; j++) acc[j] = 0.0f;

    int i = s;
    while (i < e) {
        int cnt = min(e - i, 64);
        int4 mrec = ed[i + min(lane, cnt - 1)];   // coalesced chunk prefetch
        int j = 0;
        for (; j + 2 <= cnt; j += 2) {
            int x0 = __shfl(mrec.x, j),     y0 = __shfl(mrec.y, j),     z0 = __shfl(mrec.z, j);
            int x1 = __shfl(mrec.x, j + 1), y1 = __shfl(mrec.y, j + 1), z1 = __shfl(mrec.z, j + 1);
            unsigned int u0 = tg[(size_t)y0 * 64 + lane];
            unsigned int u1 = tg[(size_t)y1 * 64 + lane];
            uint4 q0 = *(const uint4*)(xgg + ((size_t)x0 * 64 + lane) * 8);
            uint4 q1 = *(const uint4*)(xgg + ((size_t)x1 * 64 + lane) * 8);
            float lo0 = __uint_as_float(u0 << 16);
            float hi0 = __uint_as_float(u0 & 0xFFFF0000u);
            float lo1 = __uint_as_float(u1 << 16);
            float hi1 = __uint_as_float(u1 & 0xFFFF0000u);
            float wl0 = fmaf(__int_as_float(z0), hi0 - lo0, lo0);
            float wl1 = fmaf(__int_as_float(z1), hi1 - lo1, lo1);
            acc[0] = fmaf(__uint_as_float(q0.x << 16),         wl0, acc[0]);
            acc[1] = fmaf(__uint_as_float(q0.x & 0xFFFF0000u), wl0, acc[1]);
            acc[2] = fmaf(__uint_as_float(q0.y << 16),         wl0, acc[2]);
            acc[3] = fmaf(__uint_as_float(q0.y & 0xFFFF0000u), wl0, acc[3]);
            acc[4] = fmaf(__uint_as_float(q0.z << 16),         wl0, acc[4]);
            acc[5] = fmaf(__uint_as_float(q0.z & 0xFFFF0000u), wl0, acc[5]);
            acc[6] = fmaf(__uint_as_float(q0.w << 16),         wl0, acc[6]);
            acc[7] = fmaf(__uint_as_float(q0.w & 0xFFFF0000u), wl0, acc[7]);
            acc[0] = fmaf(__uint_as_float(q1.x << 16),         wl1, acc[0]);
            acc[1] = fmaf(__uint_as_float(q1.x & 0xFFFF0000u), wl1, acc[1]);
            acc[2] = fmaf(__uint_as_float(q1.y << 16),         wl1, acc[2]);
            acc[3] = fmaf(__uint_as_float(q1.y & 0xFFFF0000u), wl1, acc[3]);
            acc[4] = fmaf(__uint_as_float(q1.z << 16),         wl1, acc[4]);
            acc[5] = fmaf(__uint_as_float(q1.z & 0xFFFF0000u), wl1, acc[5]);
            acc[6] = fmaf(__uint_as_float(q1.w << 16),         wl1, acc[6]);
            acc[7] = fmaf(__uint_as_float(q1.w & 0xFFFF0000u), wl1, acc[7]);
        }
        if (j < cnt) {
            int x0 = __shfl(mrec.x, j), y0 = __shfl(mrec.y, j), z0 = __shfl(mrec.z, j);
            unsigned int u0 = tg[(size_t)y0 * 64 + lane];
            uint4 q = *(const uint4*)(xgg + ((size_t)x0 * 64 + lane) * 8);
            float lo0 = __uint_as_float(u0 << 16);
            float hi0 = __uint_as_float(u0 & 0xFFFF0000u);
            float wl = fmaf(__int_as_float(z0), hi0 - lo0, lo0);
            acc[0] = fmaf(__uint_as_float(q.x << 16),         wl, acc[0]);
            acc[1] = fmaf(__uint_as_float(q.x & 0xFFFF0000u), wl, acc[1]);
            acc[2] = fmaf(__uint_as_float(q.y << 16),         wl, acc[2]);
            acc[3] = fmaf(__uint_as_float(q.y & 0xFFFF0000u), wl, acc[3]);
            acc[4] = fmaf(__uint_as_float(q.z << 16),         wl, acc[4]);
            acc[5] = fmaf(__uint_as_float(q.z & 0xFFFF0000u), wl, acc[5]);
            acc[6] = fmaf(__uint_as_float(q.w << 16),         wl, acc[6]);
            acc[7] = fmaf(__uint_as_float(q.w & 0xFFFF0000u), wl, acc[7]);
        }
        i += cnt;
    }
    #pragma unroll
    for (int b2 = 0; b2 < 8; b2++) As[wv * 8 + b2][lane] = acc[b2];
    __syncthreads();                       // As gathered + Bs/B2 staged

    int cg = t & 15, rg = t >> 4;
    int cc0 = cg * 4, r0 = rg * 2;
    float4 bias = *(const float4*)(conv_b2 + pb * 64 + cc0);
    float a0[4] = {bias.x, bias.y, bias.z, bias.w};
    float a1[4] = {bias.x, bias.y, bias.z, bias.w};
    gemm_tile(As, Bs, r0, cc0, a0, a1);
    __syncthreads();                       // gemm1 reads of As done
    *(float4*)&As[r0][cc0] =
        make_float4(sspf(a0[0]), sspf(a0[1]), sspf(a0[2]), sspf(a0[3]));
    *(float4*)&As[r0 + 1][cc0] =
        make_float4(sspf(a1[0]), sspf(a1[1]), sspf(a1[2]), sspf(a1[3]));
    __syncthreads();                       // As=ssp ready
    float4 bb = *(const float4*)(blk_b + pb * 64 + cc0);
    float b0[4] = {bb.x, bb.y, bb.z, bb.w};
    float b1[4] = {bb.x, bb.y, bb.z, bb.w};
    gemm_tile(As, B2, r0, cc0, b0, b1);
    int dstR = perm[pbase + gi * 4 + (r0 >> 3)];
    float* dp0 = dg + ((size_t)g * NN + (size_t)(r0 & 7) * AT + dstR) * 64 + cc0;
    float* dp1 = dg + ((size_t)g * NN + (size_t)((r0 + 1) & 7) * AT + dstR) * 64 + cc0;
    *(float4*)dp0 = make_float4(b0[0], b0[1], b0[2], b0[3]);
    *(float4*)dp1 = make_float4(b1[0], b1[1], b1[2], b1[3]);
}

// Fused h-update + next-layer lin1. Non-last grid = LTOT (candidate src
// tiles; h' written by g0 for site tiles, g2 for pore tiles). Last: grid MT,
// h'-update only. cv rows precomputed in cvbuf (k_cv) — direct L2-hot loads.
__global__ __launch_bounds__(256) void k_lin1f(
    const float* __restrict__ hIn, float* __restrict__ hOut,
    const float* __restrict__ dg, const float* __restrict__ conv_w1,
    const float* __restrict__ cvbuf,
    unsigned short* __restrict__ xg, int lcur, int last) {
    __shared__ float As[TILE_M][68];
    __shared__ float Bs[64][68];
    int t = threadIdx.x;
    int g, igrp;
    if (last) { g = 0; igrp = blockIdx.x; }
    else      lin1_map(blockIdx.x, g, igrp);
    int i0 = igrp * 4;
    int writeH = last ? 1 : (g != 1);
    const float* cvl = cvbuf + (size_t)lcur * 3 * 64;
    #pragma unroll
    for (int it = 0; it < 2; it++) {
        int v = t + it * 256;
        int r = v >> 4, c4 = (v & 15) * 4;
        int k = r >> 3, b = r & 7;
        int node_i = i0 + k;
        size_t o = ((size_t)b * AT + node_i) * 64 + c4;
        float4 hv = *(const float4*)(hIn + o);
        if (node_i < M1) {
            float4 d0 = *(const float4*)(dg + o);
            float4 d2 = *(const float4*)(dg + (size_t)2 * NN * 64 + o);
            float4 c1v = *(const float4*)(cvl + 64 + c4);
            hv.x += d0.x + c1v.x + d2.x;
            hv.y += d0.y + c1v.y + d2.y;
            hv.z += d0.z + c1v.z + d2.z;
            hv.w += d0.w + c1v.w + d2.w;
        } else {
            float4 d1 = *(const float4*)(dg + (size_t)NN * 64 + o);
            float4 c0v = *(const float4*)(cvl + c4);
            float4 c2v = *(const float4*)(cvl + 128 + c4);
            hv.x += c0v.x + d1.x + c2v.x;
            hv.y += c0v.y + d1.y + c2v.y;
            hv.z += c0v.z + d1.z + c2v.z;
            hv.w += c0v.w + d1.w + c2v.w;
        }
        *(float4*)&As[r][c4] = hv;
        if (writeH) *(float4*)(hOut + o) = hv;
    }
    if (last) return;
    stage_B(conv_w1 + (size_t)((lcur + 1) * 3 + g) * 4096, Bs, t);
    __syncthreads();
    int cg = t & 15, rg = t >> 4;
    int c0 = cg * 4, r0 = rg * 2;
    float acc0[4] = {0, 0, 0, 0}, acc1[4] = {0, 0, 0, 0};
    gemm_tile(As, Bs, r0, c0, acc0, acc1);
    __syncthreads();
    *(float4*)&As[r0][c0]     = make_float4(acc0[0], acc0[1], acc0[2], acc0[3]);
    *(float4*)&As[r0 + 1][c0] = make_float4(acc1[0], acc1[1], acc1[2], acc1[3]);
    __syncthreads();
    xg_transpose_store(As, xg, g, i0, t);
}

// Readout
__global__ void k_read(const float* __restrict__ h,
                       const float* __restrict__ w1, const float* __restrict__ b1,
                       const float* __restrict__ w2, const float* __restrict__ b2,
                       float* __restrict__ out) {
    int b = blockIdx.x;
    int lane = threadIdx.x & 63;
    int wv = threadIdx.x >> 6;
    __shared__ float part[4];
    float weff = 0.0f;
    #pragma unroll
    for (int j = 0; j < H / 2; j++) weff = fmaf(w1[lane * (H / 2) + j], w2[j], weff);
    float acc = 0.0f;
    for (int i = wv * (M2 / 4); i < (wv + 1) * (M2 / 4); i++)
        acc += h[((size_t)b * AT + M1 + i) * H + lane];
    float v = acc * weff;
    for (int off = 32; off; off >>= 1) v += __shfl_xor(v, off);
    if (lane == 0) part[wv] = v;
    __syncthreads();
    if (threadIdx.x == 0) {
        float bias = b2[0];
        for (int j = 0; j < H / 2; j++) bias = fmaf(b1[j], w2[j], bias);
        out[b] = part[0] + part[1] + part[2] + part[3] + (float)M2 * bias;
    }
}

// ---------------- launcher ----------------
extern "C" void kernel_launch(void* const* d_in, const int* in_sizes, int n_in,
                              void* d_out, int out_size, void* d_ws, size_t ws_size,
                              hipStream_t stream) {
    const int* sites   = (const int*)d_in[0];
    const int* sites_p = (const int*)d_in[1];
    const int* ei1 = (const int*)d_in[2];
    const float* ew1 = (const float*)d_in[3];
    const int* c1 = (const int*)d_in[4];
    const int* ei2 = (const int*)d_in[5];
    const float* ew2 = (const float*)d_in[6];
    const int* c2 = (const int*)d_in[7];
    const int* ei3 = (const int*)d_in[8];
    const float* ew3 = (const float*)d_in[9];
    const int* c3 = (const int*)d_in[10];
    const float* emb_w   = (const float*)d_in[11];
    const float* emb_p_w = (const float*)d_in[12];
    const float* mlp_w1 = (const float*)d_in[13];
    const float* mlp_b1 = (const float*)d_in[14];
    const float* mlp_w2 = (const float*)d_in[15];
    const float* mlp_b2 = (const float*)d_in[16];
    const float* conv_w1 = (const float*)d_in[17];
    const float* conv_w2 = (const float*)d_in[18];
    const float* conv_b2 = (const float*)d_in[19];
    const float* blk_w = (const float*)d_in[20];
    const float* blk_b = (const float*)d_in[21];
    const float* out_w1 = (const float*)d_in[22];
    const float* out_b1 = (const float*)d_in[23];
    const float* out_w2 = (const float*)d_in[24];
    const float* out_b2 = (const float*)d_in[25];

    char* ws = (char*)d_ws;
    float* hA   = (float*)(ws + O_HA);
    float* hB   = (float*)(ws + O_HB);
    unsigned short* xg = (unsigned short*)(ws + O_XG);
    float* dg   = (float*)(ws + O_DG);     // tabF aliases this before layer 0
    unsigned int* tab2 = (unsigned int*)(ws + O_TAB2);
    int4*  edata = (int4*)(ws + O_EDATA);
    int* ip    = (int*)(ws + O_INT);
    int* deg   = ip + I_DEG;
    int* cur   = ip + I_CUR;
    int* ibase = ip + I_BASE;
    int* dperm = ip + I_PERM;
    float* cvbuf = (float*)(ip + I_CV);

    hipMemsetAsync(ip, 0, (size_t)I_ZEND * sizeof(int), stream);

    k_table<<<48 * NT / 4, 256, 0, stream>>>(mlp_w1, mlp_b1, mlp_w2, mlp_b2, dg);
    k_pack<<<48 * NT * 64 / 256, 256, 0, stream>>>(dg, tab2);
    k_cv<<<12, 64, 0, stream>>>(conv_b2, blk_w, blk_b, cvbuf);
    k_init_h<<<(NN * 64 + 255) / 256, 256, 0, stream>>>(sites, sites_p, emb_w, emb_p_w, hA);
    k_count<<<NBLK, 256, 0, stream>>>(ei1, ei2, ei3, c1, c2, c3, deg);
    k_scan<<<3, 256, 0, stream>>>(deg, ibase);
    k_sort<<<3, 256, 0, stream>>>(deg, dperm);
    k_fill<<<NBLK, 256, 0, stream>>>(ei1, ei2, ei3, c1, c2, c3, ew1, ew2, ew3,
                                     ibase, cur, edata);

    k_lin1t<<<LTOT, 256, 0, stream>>>(hA, conv_w1, xg, 0);
    float* hcur = hA;
    float* hnxt = hB;
    for (int l = 0; l < L; l++) {
        int last = (l == L - 1) ? 1 : 0;
        k_aggl<<<NBTOT, 256, 0, stream>>>(edata, ibase, dperm, xg, tab2,
                                          conv_w2, conv_b2, blk_w, blk_b,
                                          dg, l);
        k_lin1f<<<last ? MT : LTOT, 256, 0, stream>>>(hcur, hnxt, dg, conv_w1,
                                                      cvbuf, xg, l, last);
        float* tmp = hcur; hcur = hnxt; hnxt = tmp;
    }
    k_read<<<BS, 256, 0, stream>>>(hcur, out_w1, out_b1, out_w2, out_b2, (float*)d_out);
}

// Round 23
// 336.954 us; speedup vs baseline: 1.0756x; 1.0756x over previous
//
#include <hip/hip_runtime.h>
#include <math.h>

// ---------------- problem constants ----------------
constexpr int M1 = 2000, M2 = 400, BS = 8;
constexpr int AT = M1 + M2;            // 2400
constexpr int NN = BS * AT;            // 19200 nodes
constexpr int E1 = 60000, E2 = 20000, E3 = 20000;
constexpr int ET = E1 + E2 + E3;       // 100000
constexpr int H = 64, F = 64, NG = 50, L = 4, C = 4;
constexpr float CUTOFF = 10.0f;
constexpr float LOG2F_ = 0.6931471805599453f;

constexpr float SMEAR_STEP = 10.0f / 49.0f;
constexpr float SMEAR_COEFF = -12.005f;
constexpr float PI_OVER_CUT = 0.31415926535897932f; // pi/10

constexpr int NBLK = (ET + 255) / 256;

// Edge-MLP lerp table: packed bf16 pair {v_p, v_{p+1}} per (slice,p,feature).
// NT=256: lerp err ~(10/255)^2/8*|W''| ~ 1e-3 abs — same order as the bf16
// quantization already in the table; threshold is 1.105.
constexpr int NT = 256;
constexpr float DSCALE = (float)(NT - 1) / CUTOFF;   // 25.5

// GEMM tiling
constexpr int TILE_M = 32;
constexpr int MT = NN / TILE_M;        // 600 i-groups (AT/4)

// Candidate dst sets (gather): g0 -> [0,M1), g1 -> [M1,AT), g2 -> [0,M1)
constexpr int NB0 = M1 / 4;            // 500 blocks
constexpr int NB1 = M2 / 4;            // 100
constexpr int NB2 = M1 / 4;            // 500
constexpr int NBTOT = NB0 + NB1 + NB2; // 1100

// Candidate SRC tiles (lin1): g0,g1 srcs < M1 (500 tiles); g2 srcs >= M1 (100)
constexpr int LT0 = M1 / 4;            // 500
constexpr int LT1 = M1 / 4;            // 500
constexpr int LT2 = M2 / 4;            // 100
constexpr int LTOT = LT0 + LT1 + LT2;  // 1100

// ---------------- workspace layout (bytes) ----------------
constexpr size_t O_HA    = 0;                            // hA [NN,64] f32 (4.9MB)
constexpr size_t O_HB    = O_HA  + (size_t)NN * 64 * 4;  // hB [NN,64] f32 (4.9MB)
constexpr size_t O_XG    = O_HB  + (size_t)NN * 64 * 4;  // xg [3][AT][64][8] BF16 (7.4MB)
constexpr size_t O_DG    = O_XG  + (size_t)3 * AT * 512 * 2; // dg [3,NN,64] f32 (tabF aliases)
constexpr size_t O_TAB2  = O_DG  + (size_t)3 * NN * 64 * 4;  // tab2 [48,NT,64] uint (3.1MB)
constexpr size_t O_EDATA = O_TAB2 + (size_t)48 * NT * 64 * 4; // edata [ET] int4
constexpr size_t O_INT   = O_EDATA + (size_t)ET * 16;
constexpr int I_DEG  = 0;      // [3*AT] zeroed
constexpr int I_CUR  = 7200;   // [3*AT] zeroed
constexpr int I_ZEND = 14400;
constexpr int I_BASE = 14400;  // [3*(AT+1)] = 7203
constexpr int I_PERM = 21616;  // [4400] candidate dsts sorted by degree (per g)
constexpr int I_CV   = 26016;  // [12*64] float cv rows

__device__ inline float sspf(float x) {
    return fmaxf(x, 0.0f) + log1pf(expf(-fabsf(x))) - LOG2F_;
}
__device__ inline float sspf_fast(float x) {
    float t = __expf(-fabsf(x));
    return fmaxf(x, 0.0f) + __logf(1.0f + t) - LOG2F_;
}

// fp32 -> bf16 with round-to-nearest-even (bit manipulation, 4 VALU)
__device__ inline unsigned int bf16rn(float x) {
    unsigned int u = __float_as_uint(x);
    u = (u + 0x7FFFu + ((u >> 16) & 1u)) >> 16;
    return u & 0xFFFFu;
}

__device__ inline int graph_off(int g) { return g == 0 ? 0 : (g == 1 ? E1 : E1 + E2); }

__device__ inline void edge_decode(int idx, int& g, int& e,
                                   const int* ei1, const int* ei2, const int* ei3,
                                   const int* c1, const int* c2, const int* c3,
                                   const int*& ei, const int*& cl) {
    if (idx < E1)            { g = 0; e = idx;           ei = ei1; cl = c1; }
    else if (idx < E1 + E2)  { g = 1; e = idx - E1;      ei = ei2; cl = c2; }
    else                     { g = 2; e = idx - E1 - E2; ei = ei3; cl = c3; }
}

// ---------------- setup kernels ----------------
__global__ void k_init_h(const int* __restrict__ sites, const int* __restrict__ sites_p,
                         const float* __restrict__ emb_w, const float* __restrict__ emb_p_w,
                         float* __restrict__ h) {
    int idx = blockIdx.x * blockDim.x + threadIdx.x;
    if (idx >= NN * 64) return;
    int f = idx & 63;
    int n = idx >> 6;
    int b = n / AT;
    int i = n - b * AT;
    float v;
    if (i < M1) v = emb_w[sites[b * M1 + i] * H + f];
    else        v = emb_p_w[sites_p[b * M2 + (i - M1)] * H + f];
    h[idx] = v;
}

__global__ void k_count(const int* __restrict__ ei1, const int* __restrict__ ei2,
                        const int* __restrict__ ei3, const int* __restrict__ c1,
                        const int* __restrict__ c2, const int* __restrict__ c3,
                        int* __restrict__ deg) {
    int idx = blockIdx.x * blockDim.x + threadIdx.x;
    if (idx >= ET) return;
    int g, e; const int* ei; const int* cl;
    edge_decode(idx, g, e, ei1, ei2, ei3, c1, c2, c3, ei, cl);
    atomicAdd(&deg[g * AT + ei[2 * e + 1]], 1);
}

__global__ void k_scan(const int* __restrict__ deg, int* __restrict__ base) {
    const int T = 256, CH = 10;
    int t = threadIdx.x;
    __shared__ int lsum[T];
    int g = blockIdx.x;
    int loc[CH];
    int s = 0;
    #pragma unroll
    for (int i = 0; i < CH; i++) {
        int idx = t * CH + i;
        int v = (idx < AT) ? deg[g * AT + idx] : 0;
        loc[i] = s;
        s += v;
    }
    lsum[t] = s;
    __syncthreads();
    for (int off = 1; off < T; off <<= 1) {
        int v = 0;
        if (t >= off) v = lsum[t - off];
        __syncthreads();
        lsum[t] += v;
        __syncthreads();
    }
    int tb = lsum[t] - s;
    #pragma unroll
    for (int i = 0; i < CH; i++) {
        int idx = t * CH + i;
        if (idx < AT) base[g * (AT + 1) + idx] = tb + loc[i];
    }
    if (t == T - 1) base[g * (AT + 1) + AT] = lsum[T - 1];
}

// Counting sort (ascending degree) of each graph's CANDIDATE dsts only.
__global__ void k_sort(const int* __restrict__ deg, int* __restrict__ perm) {
    __shared__ int hist[256];
    __shared__ int cur[256];
    int g = blockIdx.x, t = threadIdx.x;
    int off   = (g == 1) ? M1 : 0;
    int cnt   = (g == 1) ? M2 : M1;
    int pbase = (g == 0) ? 0 : ((g == 1) ? M1 : (M1 + M2));
    hist[t] = 0;
    __syncthreads();
    for (int i = t; i < cnt; i += 256)
        atomicAdd(&hist[min(deg[g * AT + off + i], 255)], 1);
    __syncthreads();
    if (t == 0) {
        int run = 0;
        for (int k = 0; k < 256; k++) { cur[k] = run; run += hist[k]; }
    }
    __syncthreads();
    for (int i = t; i < cnt; i += 256) {
        int pos = atomicAdd(&cur[min(deg[g * AT + off + i], 255)], 1);
        perm[pbase + pos] = off + i;
    }
}

__global__ void k_fill(const int* __restrict__ ei1, const int* __restrict__ ei2,
                       const int* __restrict__ ei3, const int* __restrict__ c1,
                       const int* __restrict__ c2, const int* __restrict__ c3,
                       const float* __restrict__ ew1, const float* __restrict__ ew2,
                       const float* __restrict__ ew3,
                       const int* __restrict__ base, int* __restrict__ cur,
                       int4* __restrict__ edata) {
    int idx = blockIdx.x * blockDim.x + threadIdx.x;
    if (idx >= ET) return;
    int g, e; const int* ei; const int* cl;
    edge_decode(idx, g, e, ei1, ei2, ei3, c1, c2, c3, ei, cl);
    const float* ew = (g == 0) ? ew1 : (g == 1 ? ew2 : ew3);
    int dst = ei[2 * e + 1];
    int src = ei[2 * e];
    int p = base[g * (AT + 1) + dst] + atomicAdd(&cur[g * AT + dst], 1);
    float t = ew[e] * DSCALE;
    int i0 = min((int)t, NT - 2);
    float fr = t - (float)i0;
    int cb = cl[e] * (L * NT) + i0;
    edata[graph_off(g) + p] = make_int4(src, cb, __float_as_int(fr), 0);
}

// Per-(l,g) constant row cv = ssp(cb2)@bw + bb, computed ONCE (grid 12 x 64).
__global__ void k_cv(const float* __restrict__ conv_b2,
                     const float* __restrict__ blk_w,
                     const float* __restrict__ blk_b,
                     float* __restrict__ cvbuf) {
    int lane = threadIdx.x;      // 64
    int s = blockIdx.x;          // l*3+g, 0..11
    float sl = sspf(conv_b2[s * 64 + lane]);
    const float* bw = blk_w + (size_t)s * 4096;
    float a = blk_b[s * 64 + lane];
    #pragma unroll 8
    for (int k = 0; k < 64; k++)
        a = fmaf(__shfl(sl, k), bw[k * 64 + lane], a);
    cvbuf[s * 64 + lane] = a;
}

// ---------------- edge-MLP table build ----------------
// Stage 1: fp32 values (plain coalesced layout) into scratch (aliases dg).
__global__ __launch_bounds__(256) void k_table(
    const float* __restrict__ mlp_w1, const float* __restrict__ mlp_b1,
    const float* __restrict__ mlp_w2, const float* __restrict__ mlp_b2,
    float* __restrict__ tabF) {
    const int lane = threadIdx.x & 63;
    int w = blockIdx.x * 4 + (threadIdx.x >> 6);
    int s = w / NT;
    int p = w - s * NT;
    int l = s % L;
    int gc = s / L;
    int c = gc % C;
    int g = gc / C;
    float d = (float)p * (CUTOFF / (float)(NT - 1));

    size_t wb = (size_t)((l * 3 + g) * C + c);
    const float* w1 = mlp_w1 + wb * NG * F;
    const float* w2 = mlp_w2 + wb * F * F;
    float w1c[NG], w2c[F];
    #pragma unroll
    for (int k = 0; k < NG; k++) w1c[k] = w1[k * F + lane];
    #pragma unroll
    for (int k = 0; k < F; k++) w2c[k] = w2[k * F + lane];
    float b1c = mlp_b1[wb * F + lane];
    float b2c = mlp_b2[wb * F + lane];

    float dd = d - (float)lane * SMEAR_STEP;
    float av = (lane < NG) ? __expf(SMEAR_COEFF * dd * dd) : 0.0f;
    float acc = b1c;
    #pragma unroll
    for (int k = 0; k < NG; k++) acc = fmaf(__shfl(av, k), w1c[k], acc);
    float t = sspf_fast(acc);
    float acc2 = b2c;
    #pragma unroll
    for (int j = 0; j < F; j++) acc2 = fmaf(__shfl(t, j), w2c[j], acc2);
    float ccut = 0.5f * (__cosf(d * PI_OVER_CUT) + 1.0f);
    tabF[((size_t)s * NT + p) * 64 + lane] = acc2 * ccut;
}

// Stage 2: pack {bf16(v_p), bf16(v_{p+1})} into one dword per entry.
__global__ void k_pack(const float* __restrict__ tabF,
                       unsigned int* __restrict__ tab2) {
    int idx = blockIdx.x * 256 + threadIdx.x;   // 48*NT*64 entries
    int pc = idx & (NT * 64 - 1);               // position within slice
    int nxt = (pc < (NT - 1) * 64) ? idx + 64 : idx;  // p=NT-1 never sampled
    unsigned int lo = bf16rn(tabF[idx]);
    unsigned int hi = bf16rn(tabF[nxt]);
    tab2[idx] = lo | (hi << 16);
}

// ---------------- LDS-tiled GEMM machinery ----------------
__device__ inline void fma4(float acc[4], float a, const float4 b) {
    acc[0] = fmaf(a, b.x, acc[0]);
    acc[1] = fmaf(a, b.y, acc[1]);
    acc[2] = fmaf(a, b.z, acc[2]);
    acc[3] = fmaf(a, b.w, acc[3]);
}

__device__ inline void stage_B(const float* __restrict__ gB, float (*Bs)[68], int t) {
    #pragma unroll
    for (int i = 0; i < 4; i++) {
        int v = t + i * 256;
        int r = v >> 4, c4 = (v & 15) * 4;
        *(float4*)&Bs[r][c4] = *(const float4*)(gB + (size_t)r * 64 + c4);
    }
}
__device__ inline void gemm_tile(const float (*As)[68], const float (*Bs)[68],
                                 int r0, int c0, float acc0[4], float acc1[4]) {
    #pragma unroll 4
    for (int k0 = 0; k0 < 64; k0 += 4) {
        float4 a0 = *(const float4*)&As[r0][k0];
        float4 a1 = *(const float4*)&As[r0 + 1][k0];
        float4 b0 = *(const float4*)&Bs[k0][c0];
        float4 b1 = *(const float4*)&Bs[k0 + 1][c0];
        float4 b2 = *(const float4*)&Bs[k0 + 2][c0];
        float4 b3 = *(const float4*)&Bs[k0 + 3][c0];
        fma4(acc0, a0.x, b0); fma4(acc0, a0.y, b1);
        fma4(acc0, a0.z, b2); fma4(acc0, a0.w, b3);
        fma4(acc1, a1.x, b0); fma4(acc1, a1.y, b1);
        fma4(acc1, a1.z, b2); fma4(acc1, a1.w, b3);
    }
}

// Transpose-pack As[(k*8+b)][c] (f32) -> xg[((g*AT+i0+k)*64+c)*8 + b] (bf16),
// one coalesced 16B uint4 per thread.
__device__ inline void xg_transpose_store(const float (*T)[68],
                                          unsigned short* __restrict__ xg,
                                          int g, int i0, int t) {
    int k = t >> 6, c = t & 63;
    unsigned int w0 = bf16rn(T[k * 8 + 0][c]) | (bf16rn(T[k * 8 + 1][c]) << 16);
    unsigned int w1 = bf16rn(T[k * 8 + 2][c]) | (bf16rn(T[k * 8 + 3][c]) << 16);
    unsigned int w2 = bf16rn(T[k * 8 + 4][c]) | (bf16rn(T[k * 8 + 5][c]) << 16);
    unsigned int w3 = bf16rn(T[k * 8 + 6][c]) | (bf16rn(T[k * 8 + 7][c]) << 16);
    unsigned short* out = xg + (((size_t)g * AT + i0 + k) * 64 + c) * 8;
    *(uint4*)out = make_uint4(w0, w1, w2, w3);
}

// lin1 candidate-tile mapping: g0,g1 need src tiles igrp<500; g2 needs >=500.
__device__ inline void lin1_map(int bid, int& g, int& igrp) {
    if (bid < LT0)            { g = 0; igrp = bid; }
    else if (bid < LT0 + LT1) { g = 1; igrp = bid - LT0; }
    else                      { g = 2; igrp = LT0 + (bid - LT0 - LT1); }
}

// xg[g] = h @ conv_w1[0,g]; grid LTOT (candidate src tiles only)
__global__ __launch_bounds__(256) void k_lin1t(
    const float* __restrict__ h, const float* __restrict__ conv_w1,
    unsigned short* __restrict__ xg, int l) {
    __shared__ float As[TILE_M][68];
    __shared__ float Bs[64][68];
    int t = threadIdx.x;
    int g, igrp;
    lin1_map(blockIdx.x, g, igrp);
    int i0 = igrp * 4;
    #pragma unroll
    for (int it = 0; it < 2; it++) {
        int v = t + it * 256;
        int r = v >> 4, c4 = (v & 15) * 4;
        int n = (r & 7) * AT + i0 + (r >> 3);
        *(float4*)&As[r][c4] = *(const float4*)(h + (size_t)n * 64 + c4);
    }
    stage_B(conv_w1 + (size_t)(l * 3 + g) * 4096, Bs, t);
    __syncthreads();
    int cg = t & 15, rg = t >> 4;
    int c0 = cg * 4, r0 = rg * 2;
    float acc0[4] = {0, 0, 0, 0}, acc1[4] = {0, 0, 0, 0};
    gemm_tile(As, Bs, r0, c0, acc0, acc1);
    __syncthreads();
    *(float4*)&As[r0][c0]     = make_float4(acc0[0], acc0[1], acc0[2], acc0[3]);
    *(float4*)&As[r0 + 1][c0] = make_float4(acc1[0], acc1[1], acc1[2], acc1[3]);
    __syncthreads();
    xg_transpose_store(As, xg, g, i0, t);
}

// ---------------- FUSED aggregation + node GEMMs ----------------
// Grid NBTOT=1100, LPT order. Gather: lane = feature c. Per edge:
// 3 broadcast shfl + 1 dword (packed bf16 table pair) + 1 dwordx4
// (8 bf16 batches of feature c) + lerp + 8 FMA. Two LDS buffers (26KB,
// 6 blocks/CU — R22 showed the 3-buffer variant's occupancy cost loses).
__global__ __launch_bounds__(256) void k_aggl(
    const int4* __restrict__ edata, const int* __restrict__ base,
    const int* __restrict__ perm,
    const unsigned short* __restrict__ xg, const unsigned int* __restrict__ tab2,
    const float* __restrict__ conv_w2, const float* __restrict__ conv_b2,
    const float* __restrict__ blk_w, const float* __restrict__ blk_b,
    float* __restrict__ dg, int l) {
    __shared__ float As[TILE_M][68];
    __shared__ float Bs[64][68];
    int t = threadIdx.x;
    const int lane = t & 63;
    const int wv = t >> 6;
    int bid = blockIdx.x;
    int g, grp, nbg, pbase;
    if (bid < NB0)            { g = 0; grp = bid;             nbg = NB0; pbase = 0; }
    else if (bid < NB0 + NB1) { g = 1; grp = bid - NB0;       nbg = NB1; pbase = M1; }
    else                      { g = 2; grp = bid - NB0 - NB1; nbg = NB2; pbase = M1 + M2; }
    int gi = nbg - 1 - grp;               // heavy groups first (LPT)
    int dst = perm[pbase + gi * 4 + wv];
    size_t pb = (size_t)(l * 3 + g);
    stage_B(conv_w2 + pb * 4096, Bs, t);  // in flight during gather

    const int4* ed = edata + graph_off(g);
    int s = base[g * (AT + 1) + dst];
    int e = base[g * (AT + 1) + dst + 1];
    const unsigned int* tg = tab2 + ((size_t)g * C * L * NT + (size_t)l * NT) * 64;
    const unsigned short* xgg = xg + (size_t)g * AT * 512;
    float acc[8];
    #pragma unroll
    for (int j = 0; j < 8; j++) acc[j] = 0.0f;

    int i = s;
    while (i < e) {
        int cnt = min(e - i, 64);
        int4 mrec = ed[i + min(lane, cnt - 1)];   // coalesced chunk prefetch
        int j = 0;
        for (; j + 2 <= cnt; j += 2) {
            int x0 = __shfl(mrec.x, j),     y0 = __shfl(mrec.y, j),     z0 = __shfl(mrec.z, j);
            int x1 = __shfl(mrec.x, j + 1), y1 = __shfl(mrec.y, j + 1), z1 = __shfl(mrec.z, j + 1);
            unsigned int u0 = tg[(size_t)y0 * 64 + lane];
            unsigned int u1 = tg[(size_t)y1 * 64 + lane];
            uint4 q0 = *(const uint4*)(xgg + ((size_t)x0 * 64 + lane) * 8);
            uint4 q1 = *(const uint4*)(xgg + ((size_t)x1 * 64 + lane) * 8);
            float lo0 = __uint_as_float(u0 << 16);
            float hi0 = __uint_as_float(u0 & 0xFFFF0000u);
            float lo1 = __uint_as_float(u1 << 16);
            float hi1 = __uint_as_float(u1 & 0xFFFF0000u);
            float wl0 = fmaf(__int_as_float(z0), hi0 - lo0, lo0);
            float wl1 = fmaf(__int_as_float(z1), hi1 - lo1, lo1);
            acc[0] = fmaf(__uint_as_float(q0.x << 16),         wl0, acc[0]);
            acc[1] = fmaf(__uint_as_float(q0.x & 0xFFFF0000u), wl0, acc[1]);
            acc[2] = fmaf(__uint_as_float(q0.y << 16),         wl0, acc[2]);
            acc[3] = fmaf(__uint_as_float(q0.y & 0xFFFF0000u), wl0, acc[3]);
            acc[4] = fmaf(__uint_as_float(q0.z << 16),         wl0, acc[4]);
            acc[5] = fmaf(__uint_as_float(q0.z & 0xFFFF0000u), wl0, acc[5]);
            acc[6] = fmaf(__uint_as_float(q0.w << 16),         wl0, acc[6]);
            acc[7] = fmaf(__uint_as_float(q0.w & 0xFFFF0000u), wl0, acc[7]);
            acc[0] = fmaf(__uint_as_float(q1.x << 16),         wl1, acc[0]);
            acc[1] = fmaf(__uint_as_float(q1.x & 0xFFFF0000u), wl1, acc[1]);
            acc[2] = fmaf(__uint_as_float(q1.y << 16),         wl1, acc[2]);
            acc[3] = fmaf(__uint_as_float(q1.y & 0xFFFF0000u), wl1, acc[3]);
            acc[4] = fmaf(__uint_as_float(q1.z << 16),         wl1, acc[4]);
            acc[5] = fmaf(__uint_as_float(q1.z & 0xFFFF0000u), wl1, acc[5]);
            acc[6] = fmaf(__uint_as_float(q1.w << 16),         wl1, acc[6]);
            acc[7] = fmaf(__uint_as_float(q1.w & 0xFFFF0000u), wl1, acc[7]);
        }
        if (j < cnt) {
            int x0 = __shfl(mrec.x, j), y0 = __shfl(mrec.y, j), z0 = __shfl(mrec.z, j);
            unsigned int u0 = tg[(size_t)y0 * 64 + lane];
            uint4 q = *(const uint4*)(xgg + ((size_t)x0 * 64 + lane) * 8);
            float lo0 = __uint_as_float(u0 << 16);
            float hi0 = __uint_as_float(u0 & 0xFFFF0000u);
            float wl = fmaf(__int_as_float(z0), hi0 - lo0, lo0);
            acc[0] = fmaf(__uint_as_float(q.x << 16),         wl, acc[0]);
            acc[1] = fmaf(__uint_as_float(q.x & 0xFFFF0000u), wl, acc[1]);
            acc[2] = fmaf(__uint_as_float(q.y << 16),         wl, acc[2]);
            acc[3] = fmaf(__uint_as_float(q.y & 0xFFFF0000u), wl, acc[3]);
            acc[4] = fmaf(__uint_as_float(q.z << 16),         wl, acc[4]);
            acc[5] = fmaf(__uint_as_float(q.z & 0xFFFF0000u), wl, acc[5]);
            acc[6] = fmaf(__uint_as_float(q.w << 16),         wl, acc[6]);
            acc[7] = fmaf(__uint_as_float(q.w & 0xFFFF0000u), wl, acc[7]);
        }
        i += cnt;
    }
    #pragma unroll
    for (int b2 = 0; b2 < 8; b2++) As[wv * 8 + b2][lane] = acc[b2];
    __syncthreads();                       // As gathered + Bs(cw2) staged

    int cg = t & 15, rg = t >> 4;
    int cc0 = cg * 4, r0 = rg * 2;
    float4 bias = *(const float4*)(conv_b2 + pb * 64 + cc0);
    float a0[4] = {bias.x, bias.y, bias.z, bias.w};
    float a1[4] = {bias.x, bias.y, bias.z, bias.w};
    gemm_tile(As, Bs, r0, cc0, a0, a1);
    __syncthreads();                       // gemm1 reads of As/Bs done
    *(float4*)&As[r0][cc0] =
        make_float4(sspf(a0[0]), sspf(a0[1]), sspf(a0[2]), sspf(a0[3]));
    *(float4*)&As[r0 + 1][cc0] =
        make_float4(sspf(a1[0]), sspf(a1[1]), sspf(a1[2]), sspf(a1[3]));
    stage_B(blk_w + pb * 4096, Bs, t);     // overwrite Bs (reads drained)
    __syncthreads();                       // As=ssp + Bs=blk_w ready
    float4 bb = *(const float4*)(blk_b + pb * 64 + cc0);
    float b0[4] = {bb.x, bb.y, bb.z, bb.w};
    float b1[4] = {bb.x, bb.y, bb.z, bb.w};
    gemm_tile(As, Bs, r0, cc0, b0, b1);
    int dstR = perm[pbase + gi * 4 + (r0 >> 3)];
    float* dp0 = dg + ((size_t)g * NN + (size_t)(r0 & 7) * AT + dstR) * 64 + cc0;
    float* dp1 = dg + ((size_t)g * NN + (size_t)((r0 + 1) & 7) * AT + dstR) * 64 + cc0;
    *(float4*)dp0 = make_float4(b0[0], b0[1], b0[2], b0[3]);
    *(float4*)dp1 = make_float4(b1[0], b1[1], b1[2], b1[3]);
}

// Fused h-update + next-layer lin1. Non-last grid = LTOT (candidate src
// tiles; h' written by g0 for site tiles, g2 for pore tiles). Last: grid MT,
// h'-update only. cv rows precomputed in cvbuf (k_cv) — direct L2-hot loads.
__global__ __launch_bounds__(256) void k_lin1f(
    const float* __restrict__ hIn, float* __restrict__ hOut,
    const float* __restrict__ dg, const float* __restrict__ conv_w1,
    const float* __restrict__ cvbuf,
    unsigned short* __restrict__ xg, int lcur, int last) {
    __shared__ float As[TILE_M][68];
    __shared__ float Bs[64][68];
    int t = threadIdx.x;
    int g, igrp;
    if (last) { g = 0; igrp = blockIdx.x; }
    else      lin1_map(blockIdx.x, g, igrp);
    int i0 = igrp * 4;
    int writeH = last ? 1 : (g != 1);
    const float* cvl = cvbuf + (size_t)lcur * 3 * 64;
    #pragma unroll
    for (int it = 0; it < 2; it++) {
        int v = t + it * 256;
        int r = v >> 4, c4 = (v & 15) * 4;
        int k = r >> 3, b = r & 7;
        int node_i = i0 + k;
        size_t o = ((size_t)b * AT + node_i) * 64 + c4;
        float4 hv = *(const float4*)(hIn + o);
        if (node_i < M1) {
            float4 d0 = *(const float4*)(dg + o);
            float4 d2 = *(const float4*)(dg + (size_t)2 * NN * 64 + o);
            float4 c1v = *(const float4*)(cvl + 64 + c4);
            hv.x += d0.x + c1v.x + d2.x;
            hv.y += d0.y + c1v.y + d2.y;
            hv.z += d0.z + c1v.z + d2.z;
            hv.w += d0.w + c1v.w + d2.w;
        } else {
            float4 d1 = *(const float4*)(dg + (size_t)NN * 64 + o);
            float4 c0v = *(const float4*)(cvl + c4);
            float4 c2v = *(const float4*)(cvl + 128 + c4);
            hv.x += c0v.x + d1.x + c2v.x;
            hv.y += c0v.y + d1.y + c2v.y;
            hv.z += c0v.z + d1.z + c2v.z;
            hv.w += c0v.w + d1.w + c2v.w;
        }
        *(float4*)&As[r][c4] = hv;
        if (writeH) *(float4*)(hOut + o) = hv;
    }
    if (last) return;
    stage_B(conv_w1 + (size_t)((lcur + 1) * 3 + g) * 4096, Bs, t);
    __syncthreads();
    int cg = t & 15, rg = t >> 4;
    int c0 = cg * 4, r0 = rg * 2;
    float acc0[4] = {0, 0, 0, 0}, acc1[4] = {0, 0, 0, 0};
    gemm_tile(As, Bs, r0, c0, acc0, acc1);
    __syncthreads();
    *(float4*)&As[r0][c0]     = make_float4(acc0[0], acc0[1], acc0[2], acc0[3]);
    *(float4*)&As[r0 + 1][c0] = make_float4(acc1[0], acc1[1], acc1[2], acc1[3]);
    __syncthreads();
    xg_transpose_store(As, xg, g, i0, t);
}

// Readout
__global__ void k_read(const float* __restrict__ h,
                       const float* __restrict__ w1, const float* __restrict__ b1,
                       const float* __restrict__ w2, const float* __restrict__ b2,
                       float* __restrict__ out) {
    int b = blockIdx.x;
    int lane = threadIdx.x & 63;
    int wv = threadIdx.x >> 6;
    __shared__ float part[4];
    float weff = 0.0f;
    #pragma unroll
    for (int j = 0; j < H / 2; j++) weff = fmaf(w1[lane * (H / 2) + j], w2[j], weff);
    float acc = 0.0f;
    for (int i = wv * (M2 / 4); i < (wv + 1) * (M2 / 4); i++)
        acc += h[((size_t)b * AT + M1 + i) * H + lane];
    float v = acc * weff;
    for (int off = 32; off; off >>= 1) v += __shfl_xor(v, off);
    if (lane == 0) part[wv] = v;
    __syncthreads();
    if (threadIdx.x == 0) {
        float bias = b2[0];
        for (int j = 0; j < H / 2; j++) bias = fmaf(b1[j], w2[j], bias);
        out[b] = part[0] + part[1] + part[2] + part[3] + (float)M2 * bias;
    }
}

// ---------------- launcher ----------------
extern "C" void kernel_launch(void* const* d_in, const int* in_sizes, int n_in,
                              void* d_out, int out_size, void* d_ws, size_t ws_size,
                              hipStream_t stream) {
    const int* sites   = (const int*)d_in[0];
    const int* sites_p = (const int*)d_in[1];
    const int* ei1 = (const int*)d_in[2];
    const float* ew1 = (const float*)d_in[3];
    const int* c1 = (const int*)d_in[4];
    const int* ei2 = (const int*)d_in[5];
    const float* ew2 = (const float*)d_in[6];
    const int* c2 = (const int*)d_in[7];
    const int* ei3 = (const int*)d_in[8];
    const float* ew3 = (const float*)d_in[9];
    const int* c3 = (const int*)d_in[10];
    const float* emb_w   = (const float*)d_in[11];
    const float* emb_p_w = (const float*)d_in[12];
    const float* mlp_w1 = (const float*)d_in[13];
    const float* mlp_b1 = (const float*)d_in[14];
    const float* mlp_w2 = (const float*)d_in[15];
    const float* mlp_b2 = (const float*)d_in[16];
    const float* conv_w1 = (const float*)d_in[17];
    const float* conv_w2 = (const float*)d_in[18];
    const float* conv_b2 = (const float*)d_in[19];
    const float* blk_w = (const float*)d_in[20];
    const float* blk_b = (const float*)d_in[21];
    const float* out_w1 = (const float*)d_in[22];
    const float* out_b1 = (const float*)d_in[23];
    const float* out_w2 = (const float*)d_in[24];
    const float* out_b2 = (const float*)d_in[25];

    char* ws = (char*)d_ws;
    float* hA   = (float*)(ws + O_HA);
    float* hB   = (float*)(ws + O_HB);
    unsigned short* xg = (unsigned short*)(ws + O_XG);
    float* dg   = (float*)(ws + O_DG);     // tabF aliases this before layer 0
    unsigned int* tab2 = (unsigned int*)(ws + O_TAB2);
    int4*  edata = (int4*)(ws + O_EDATA);
    int* ip    = (int*)(ws + O_INT);
    int* deg   = ip + I_DEG;
    int* cur   = ip + I_CUR;
    int* ibase = ip + I_BASE;
    int* dperm = ip + I_PERM;
    float* cvbuf = (float*)(ip + I_CV);

    hipMemsetAsync(ip, 0, (size_t)I_ZEND * sizeof(int), stream);

    k_table<<<48 * NT / 4, 256, 0, stream>>>(mlp_w1, mlp_b1, mlp_w2, mlp_b2, dg);
    k_pack<<<48 * NT * 64 / 256, 256, 0, stream>>>(dg, tab2);
    k_cv<<<12, 64, 0, stream>>>(conv_b2, blk_w, blk_b, cvbuf);
    k_init_h<<<(NN * 64 + 255) / 256, 256, 0, stream>>>(sites, sites_p, emb_w, emb_p_w, hA);
    k_count<<<NBLK, 256, 0, stream>>>(ei1, ei2, ei3, c1, c2, c3, deg);
    k_scan<<<3, 256, 0, stream>>>(deg, ibase);
    k_sort<<<3, 256, 0, stream>>>(deg, dperm);
    k_fill<<<NBLK, 256, 0, stream>>>(ei1, ei2, ei3, c1, c2, c3, ew1, ew2, ew3,
                                     ibase, cur, edata);

    k_lin1t<<<LTOT, 256, 0, stream>>>(hA, conv_w1, xg, 0);
    float* hcur = hA;
    float* hnxt = hB;
    for (int l = 0; l < L; l++) {
        int last = (l == L - 1) ? 1 : 0;
        k_aggl<<<NBTOT, 256, 0, stream>>>(edata, ibase, dperm, xg, tab2,
                                          conv_w2, conv_b2, blk_w, blk_b,
                                          dg, l);
        k_lin1f<<<last ? MT : LTOT, 256, 0, stream>>>(hcur, hnxt, dg, conv_w1,
                                                      cvbuf, xg, l, last);
        float* tmp = hcur; hcur = hnxt; hnxt = tmp;
    }
    k_read<<<BS, 256, 0, stream>>>(hcur, out_w1, out_b1, out_w2, out_b2, (float*)d_out);
}

// Round 24
// 322.409 us; speedup vs baseline: 1.1241x; 1.0451x over previous
//
#include <hip/hip_runtime.h>
#include <math.h>

// ---------------- problem constants ----------------
constexpr int M1 = 2000, M2 = 400, BS = 8;
constexpr int AT = M1 + M2;            // 2400
constexpr int NN = BS * AT;            // 19200 nodes
constexpr int E1 = 60000, E2 = 20000, E3 = 20000;
constexpr int ET = E1 + E2 + E3;       // 100000
constexpr int H = 64, F = 64, NG = 50, L = 4, C = 4;
constexpr float CUTOFF = 10.0f;
constexpr float LOG2F_ = 0.6931471805599453f;

constexpr float SMEAR_STEP = 10.0f / 49.0f;
constexpr float SMEAR_COEFF = -12.005f;
constexpr float PI_OVER_CUT = 0.31415926535897932f; // pi/10

constexpr int NBLK = (ET + 255) / 256;  // 391

// Edge-MLP lerp table: packed bf16 pair {v_p, v_{p+1}} per (slice,p,feature).
constexpr int NT = 256;
constexpr float DSCALE = (float)(NT - 1) / CUTOFF;   // 25.5

// GEMM tiling
constexpr int TILE_M = 32;
constexpr int MT = NN / TILE_M;        // 600 i-groups (AT/4)

// Candidate dst sets (gather): g0 -> [0,M1), g1 -> [M1,AT), g2 -> [0,M1)
constexpr int NB0 = M1 / 4;            // 500 blocks
constexpr int NB1 = M2 / 4;            // 100
constexpr int NB2 = M1 / 4;            // 500
constexpr int NBTOT = NB0 + NB1 + NB2; // 1100

// Candidate SRC tiles (lin1): g0,g1 srcs < M1 (500 tiles); g2 srcs >= M1 (100)
constexpr int LT0 = M1 / 4;            // 500
constexpr int LT1 = M1 / 4;            // 500
constexpr int LT2 = M2 / 4;            // 100
constexpr int LTOT = LT0 + LT1 + LT2;  // 1100

// Merged setup kernel A block ranges
constexpr int A_TAB  = 48 * NT / 4;          // 3072 (table)
constexpr int A_INIT = NN * 64 / 256;        // 4800 (init_h)
constexpr int A_CNT  = NBLK;                 // 391  (count)
constexpr int A_CV   = 3;                    // 12 slices, 4 waves/block
constexpr int A_TOT  = A_TAB + A_INIT + A_CNT + A_CV;
// Merged setup kernel B block ranges
constexpr int B_PACK = 48 * NT * 64 / 256;   // 3072 (pack)
constexpr int B_TOT  = B_PACK + 3 + 3;       // + scan(3) + sort(3)

// ---------------- workspace layout (bytes) ----------------
constexpr size_t O_HA    = 0;                            // hA [NN,64] f32 (4.9MB)
constexpr size_t O_HB    = O_HA  + (size_t)NN * 64 * 4;  // hB [NN,64] f32 (4.9MB)
constexpr size_t O_XG    = O_HB  + (size_t)NN * 64 * 4;  // xg [3][AT][64][8] BF16 (7.4MB)
constexpr size_t O_DG    = O_XG  + (size_t)3 * AT * 512 * 2; // dg [3,NN,64] f32 (tabF aliases)
constexpr size_t O_TAB2  = O_DG  + (size_t)3 * NN * 64 * 4;  // tab2 [48,NT,64] uint (3.1MB)
constexpr size_t O_EDATA = O_TAB2 + (size_t)48 * NT * 64 * 4; // edata [ET] int4
constexpr size_t O_INT   = O_EDATA + (size_t)ET * 16;
constexpr int I_DEG  = 0;      // [3*AT] zeroed
constexpr int I_CUR  = 7200;   // [3*AT] zeroed
constexpr int I_ZEND = 14400;
constexpr int I_BASE = 14400;  // [3*(AT+1)] = 7203
constexpr int I_PERM = 21616;  // [4400] candidate dsts sorted by degree (per g)
constexpr int I_CV   = 26016;  // [12*64] float cv rows

__device__ inline float sspf(float x) {
    return fmaxf(x, 0.0f) + log1pf(expf(-fabsf(x))) - LOG2F_;
}
__device__ inline float sspf_fast(float x) {
    float t = __expf(-fabsf(x));
    return fmaxf(x, 0.0f) + __logf(1.0f + t) - LOG2F_;
}

// fp32 -> bf16 with round-to-nearest-even (bit manipulation, 4 VALU)
__device__ inline unsigned int bf16rn(float x) {
    unsigned int u = __float_as_uint(x);
    u = (u + 0x7FFFu + ((u >> 16) & 1u)) >> 16;
    return u & 0xFFFFu;
}

__device__ inline int graph_off(int g) { return g == 0 ? 0 : (g == 1 ? E1 : E1 + E2); }

__device__ inline void edge_decode(int idx, int& g, int& e,
                                   const int* ei1, const int* ei2, const int* ei3,
                                   const int* c1, const int* c2, const int* c3,
                                   const int*& ei, const int*& cl) {
    if (idx < E1)            { g = 0; e = idx;           ei = ei1; cl = c1; }
    else if (idx < E1 + E2)  { g = 1; e = idx - E1;      ei = ei2; cl = c2; }
    else                     { g = 2; e = idx - E1 - E2; ei = ei3; cl = c3; }
}

// ---------------- merged setup kernel A ----------------
// Independent jobs dispatched by block range:
//   [0,A_TAB): edge-MLP table (fp32 -> tabF scratch)
//   [A_TAB, +A_INIT): h init
//   [.., +A_CNT): dst-degree count
//   [.., +A_CV): per-(l,g) constant rows cv = ssp(cb2)@bw+bb
__global__ __launch_bounds__(256) void k_setupA(
    const float* __restrict__ mlp_w1, const float* __restrict__ mlp_b1,
    const float* __restrict__ mlp_w2, const float* __restrict__ mlp_b2,
    float* __restrict__ tabF,
    const int* __restrict__ sites, const int* __restrict__ sites_p,
    const float* __restrict__ emb_w, const float* __restrict__ emb_p_w,
    float* __restrict__ h,
    const int* __restrict__ ei1, const int* __restrict__ ei2,
    const int* __restrict__ ei3, const int* __restrict__ c1,
    const int* __restrict__ c2, const int* __restrict__ c3,
    int* __restrict__ deg,
    const float* __restrict__ conv_b2, const float* __restrict__ blk_w,
    const float* __restrict__ blk_b, float* __restrict__ cvbuf) {
    int bid = blockIdx.x;
    int t = threadIdx.x;
    if (bid < A_TAB) {
        // ---- table job ----
        const int lane = t & 63;
        int w = bid * 4 + (t >> 6);
        int s = w / NT;
        int p = w - s * NT;
        int l = s % L;
        int gc = s / L;
        int c = gc % C;
        int g = gc / C;
        float d = (float)p * (CUTOFF / (float)(NT - 1));
        size_t wb = (size_t)((l * 3 + g) * C + c);
        const float* w1 = mlp_w1 + wb * NG * F;
        const float* w2 = mlp_w2 + wb * F * F;
        float w1c[NG], w2c[F];
        #pragma unroll
        for (int k = 0; k < NG; k++) w1c[k] = w1[k * F + lane];
        #pragma unroll
        for (int k = 0; k < F; k++) w2c[k] = w2[k * F + lane];
        float b1c = mlp_b1[wb * F + lane];
        float b2c = mlp_b2[wb * F + lane];
        float dd = d - (float)lane * SMEAR_STEP;
        float av = (lane < NG) ? __expf(SMEAR_COEFF * dd * dd) : 0.0f;
        float acc = b1c;
        #pragma unroll
        for (int k = 0; k < NG; k++) acc = fmaf(__shfl(av, k), w1c[k], acc);
        float tt = sspf_fast(acc);
        float acc2 = b2c;
        #pragma unroll
        for (int j = 0; j < F; j++) acc2 = fmaf(__shfl(tt, j), w2c[j], acc2);
        float ccut = 0.5f * (__cosf(d * PI_OVER_CUT) + 1.0f);
        tabF[((size_t)s * NT + p) * 64 + lane] = acc2 * ccut;
    } else if (bid < A_TAB + A_INIT) {
        // ---- init_h job ----
        int idx = (bid - A_TAB) * 256 + t;
        int f = idx & 63;
        int n = idx >> 6;
        int b = n / AT;
        int i = n - b * AT;
        float v;
        if (i < M1) v = emb_w[sites[b * M1 + i] * H + f];
        else        v = emb_p_w[sites_p[b * M2 + (i - M1)] * H + f];
        h[idx] = v;
    } else if (bid < A_TAB + A_INIT + A_CNT) {
        // ---- count job ----
        int idx = (bid - A_TAB - A_INIT) * 256 + t;
        if (idx < ET) {
            int g, e; const int* ei; const int* cl;
            edge_decode(idx, g, e, ei1, ei2, ei3, c1, c2, c3, ei, cl);
            atomicAdd(&deg[g * AT + ei[2 * e + 1]], 1);
        }
    } else {
        // ---- cv job: 3 blocks x 4 waves = 12 slices ----
        int s = (bid - A_TAB - A_INIT - A_CNT) * 4 + (t >> 6);
        int lane = t & 63;
        if (s < 12) {
            float sl = sspf(conv_b2[s * 64 + lane]);
            const float* bw = blk_w + (size_t)s * 4096;
            float a = blk_b[s * 64 + lane];
            #pragma unroll 8
            for (int k = 0; k < 64; k++)
                a = fmaf(__shfl(sl, k), bw[k * 64 + lane], a);
            cvbuf[s * 64 + lane] = a;
        }
    }
}

// ---------------- merged setup kernel B ----------------
//   [0, B_PACK): bf16-pack the table
//   [B_PACK, +3): exclusive degree scan -> base (one block per graph)
//   [B_PACK+3, +3): candidate counting sort -> perm (one block per graph)
__global__ __launch_bounds__(256) void k_setupB(
    const float* __restrict__ tabF, unsigned int* __restrict__ tab2,
    const int* __restrict__ deg, int* __restrict__ base,
    int* __restrict__ perm) {
    int bid = blockIdx.x;
    int t = threadIdx.x;
    if (bid < B_PACK) {
        int idx = bid * 256 + t;
        int pc = idx & (NT * 64 - 1);
        int nxt = (pc < (NT - 1) * 64) ? idx + 64 : idx;
        unsigned int lo = bf16rn(tabF[idx]);
        unsigned int hi = bf16rn(tabF[nxt]);
        tab2[idx] = lo | (hi << 16);
    } else if (bid < B_PACK + 3) {
        const int T = 256, CH = 10;
        __shared__ int lsum[256];
        int g = bid - B_PACK;
        int loc[CH];
        int s = 0;
        #pragma unroll
        for (int i = 0; i < CH; i++) {
            int idx = t * CH + i;
            int v = (idx < AT) ? deg[g * AT + idx] : 0;
            loc[i] = s;
            s += v;
        }
        lsum[t] = s;
        __syncthreads();
        for (int off = 1; off < T; off <<= 1) {
            int v = 0;
            if (t >= off) v = lsum[t - off];
            __syncthreads();
            lsum[t] += v;
            __syncthreads();
        }
        int tb = lsum[t] - s;
        #pragma unroll
        for (int i = 0; i < CH; i++) {
            int idx = t * CH + i;
            if (idx < AT) base[g * (AT + 1) + idx] = tb + loc[i];
        }
        if (t == T - 1) base[g * (AT + 1) + AT] = lsum[T - 1];
    } else {
        __shared__ int hist[256];
        __shared__ int cur[256];
        int g = bid - B_PACK - 3;
        int off   = (g == 1) ? M1 : 0;
        int cnt   = (g == 1) ? M2 : M1;
        int pbase = (g == 0) ? 0 : ((g == 1) ? M1 : (M1 + M2));
        hist[t] = 0;
        __syncthreads();
        for (int i = t; i < cnt; i += 256)
            atomicAdd(&hist[min(deg[g * AT + off + i], 255)], 1);
        __syncthreads();
        if (t == 0) {
            int run = 0;
            for (int k = 0; k < 256; k++) { cur[k] = run; run += hist[k]; }
        }
        __syncthreads();
        for (int i = t; i < cnt; i += 256) {
            int pos = atomicAdd(&cur[min(deg[g * AT + off + i], 255)], 1);
            perm[pbase + pos] = off + i;
        }
    }
}

__global__ void k_fill(const int* __restrict__ ei1, const int* __restrict__ ei2,
                       const int* __restrict__ ei3, const int* __restrict__ c1,
                       const int* __restrict__ c2, const int* __restrict__ c3,
                       const float* __restrict__ ew1, const float* __restrict__ ew2,
                       const float* __restrict__ ew3,
                       const int* __restrict__ base, int* __restrict__ cur,
                       int4* __restrict__ edata) {
    int idx = blockIdx.x * blockDim.x + threadIdx.x;
    if (idx >= ET) return;
    int g, e; const int* ei; const int* cl;
    edge_decode(idx, g, e, ei1, ei2, ei3, c1, c2, c3, ei, cl);
    const float* ew = (g == 0) ? ew1 : (g == 1 ? ew2 : ew3);
    int dst = ei[2 * e + 1];
    int src = ei[2 * e];
    int p = base[g * (AT + 1) + dst] + atomicAdd(&cur[g * AT + dst], 1);
    float t = ew[e] * DSCALE;
    int i0 = min((int)t, NT - 2);
    float fr = t - (float)i0;
    int cb = cl[e] * (L * NT) + i0;
    edata[graph_off(g) + p] = make_int4(src, cb, __float_as_int(fr), 0);
}

// ---------------- LDS-tiled GEMM machinery ----------------
__device__ inline void fma4(float acc[4], float a, const float4 b) {
    acc[0] = fmaf(a, b.x, acc[0]);
    acc[1] = fmaf(a, b.y, acc[1]);
    acc[2] = fmaf(a, b.z, acc[2]);
    acc[3] = fmaf(a, b.w, acc[3]);
}

__device__ inline void stage_B(const float* __restrict__ gB, float (*Bs)[68], int t) {
    #pragma unroll
    for (int i = 0; i < 4; i++) {
        int v = t + i * 256;
        int r = v >> 4, c4 = (v & 15) * 4;
        *(float4*)&Bs[r][c4] = *(const float4*)(gB + (size_t)r * 64 + c4);
    }
}
__device__ inline void gemm_tile(const float (*As)[68], const float (*Bs)[68],
                                 int r0, int c0, float acc0[4], float acc1[4]) {
    #pragma unroll 4
    for (int k0 = 0; k0 < 64; k0 += 4) {
        float4 a0 = *(const float4*)&As[r0][k0];
        float4 a1 = *(const float4*)&As[r0 + 1][k0];
        float4 b0 = *(const float4*)&Bs[k0][c0];
        float4 b1 = *(const float4*)&Bs[k0 + 1][c0];
        float4 b2 = *(const float4*)&Bs[k0 + 2][c0];
        float4 b3 = *(const float4*)&Bs[k0 + 3][c0];
        fma4(acc0, a0.x, b0); fma4(acc0, a0.y, b1);
        fma4(acc0, a0.z, b2); fma4(acc0, a0.w, b3);
        fma4(acc1, a1.x, b0); fma4(acc1, a1.y, b1);
        fma4(acc1, a1.z, b2); fma4(acc1, a1.w, b3);
    }
}

// Transpose-pack As[(k*8+b)][c] (f32) -> xg[((g*AT+i0+k)*64+c)*8 + b] (bf16),
// one coalesced 16B uint4 per thread.
__device__ inline void xg_transpose_store(const float (*T)[68],
                                          unsigned short* __restrict__ xg,
                                          int g, int i0, int t) {
    int k = t >> 6, c = t & 63;
    unsigned int w0 = bf16rn(T[k * 8 + 0][c]) | (bf16rn(T[k * 8 + 1][c]) << 16);
    unsigned int w1 = bf16rn(T[k * 8 + 2][c]) | (bf16rn(T[k * 8 + 3][c]) << 16);
    unsigned int w2 = bf16rn(T[k * 8 + 4][c]) | (bf16rn(T[k * 8 + 5][c]) << 16);
    unsigned int w3 = bf16rn(T[k * 8 + 6][c]) | (bf16rn(T[k * 8 + 7][c]) << 16);
    unsigned short* out = xg + (((size_t)g * AT + i0 + k) * 64 + c) * 8;
    *(uint4*)out = make_uint4(w0, w1, w2, w3);
}

// lin1 candidate-tile mapping: g0,g1 need src tiles igrp<500; g2 needs >=500.
__device__ inline void lin1_map(int bid, int& g, int& igrp) {
    if (bid < LT0)            { g = 0; igrp = bid; }
    else if (bid < LT0 + LT1) { g = 1; igrp = bid - LT0; }
    else                      { g = 2; igrp = LT0 + (bid - LT0 - LT1); }
}

// xg[g] = h @ conv_w1[0,g]; grid LTOT (candidate src tiles only)
__global__ __launch_bounds__(256) void k_lin1t(
    const float* __restrict__ h, const float* __restrict__ conv_w1,
    unsigned short* __restrict__ xg, int l) {
    __shared__ float As[TILE_M][68];
    __shared__ float Bs[64][68];
    int t = threadIdx.x;
    int g, igrp;
    lin1_map(blockIdx.x, g, igrp);
    int i0 = igrp * 4;
    #pragma unroll
    for (int it = 0; it < 2; it++) {
        int v = t + it * 256;
        int r = v >> 4, c4 = (v & 15) * 4;
        int n = (r & 7) * AT + i0 + (r >> 3);
        *(float4*)&As[r][c4] = *(const float4*)(h + (size_t)n * 64 + c4);
    }
    stage_B(conv_w1 + (size_t)(l * 3 + g) * 4096, Bs, t);
    __syncthreads();
    int cg = t & 15, rg = t >> 4;
    int c0 = cg * 4, r0 = rg * 2;
    float acc0[4] = {0, 0, 0, 0}, acc1[4] = {0, 0, 0, 0};
    gemm_tile(As, Bs, r0, c0, acc0, acc1);
    __syncthreads();
    *(float4*)&As[r0][c0]     = make_float4(acc0[0], acc0[1], acc0[2], acc0[3]);
    *(float4*)&As[r0 + 1][c0] = make_float4(acc1[0], acc1[1], acc1[2], acc1[3]);
    __syncthreads();
    xg_transpose_store(As, xg, g, i0, t);
}

// ---------------- FUSED aggregation + node GEMMs ----------------
// Grid NBTOT=1100, LPT order. Gather: lane = feature c. Per edge:
// 3 broadcast shfl + 1 dword (packed bf16 table pair) + 1 dwordx4
// (8 bf16 batches of feature c) + lerp + 8 FMA. Two LDS buffers (26KB,
// 6 blocks/CU — R22 showed the 3-buffer variant's occupancy cost loses).
__global__ __launch_bounds__(256) void k_aggl(
    const int4* __restrict__ edata, const int* __restrict__ base,
    const int* __restrict__ perm,
    const unsigned short* __restrict__ xg, const unsigned int* __restrict__ tab2,
    const float* __restrict__ conv_w2, const float* __restrict__ conv_b2,
    const float* __restrict__ blk_w, const float* __restrict__ blk_b,
    float* __restrict__ dg, int l) {
    __shared__ float As[TILE_M][68];
    __shared__ float Bs[64][68];
    int t = threadIdx.x;
    const int lane = t & 63;
    const int wv = t >> 6;
    int bid = blockIdx.x;
    int g, grp, nbg, pbase;
    if (bid < NB0)            { g = 0; grp = bid;             nbg = NB0; pbase = 0; }
    else if (bid < NB0 + NB1) { g = 1; grp = bid - NB0;       nbg = NB1; pbase = M1; }
    else                      { g = 2; grp = bid - NB0 - NB1; nbg = NB2; pbase = M1 + M2; }
    int gi = nbg - 1 - grp;               // heavy groups first (LPT)
    int dst = perm[pbase + gi * 4 + wv];
    size_t pb = (size_t)(l * 3 + g);
    stage_B(conv_w2 + pb * 4096, Bs, t);  // in flight during gather

    const int4* ed = edata + graph_off(g);
    int s = base[g * (AT + 1) + dst];
    int e = base[g * (AT + 1) + dst + 1];
    const unsigned int* tg = tab2 + ((size_t)g * C * L * NT + (size_t)l * NT) * 64;
    const unsigned short* xgg = xg + (size_t)g * AT * 512;
    float acc[8];
    #pragma unroll
    for (int j = 0; j < 8; j++) acc[j] = 0.0f;

    int i = s;
    while (i < e) {
        int cnt = min(e - i, 64);
        int4 mrec = ed[i + min(lane, cnt - 1)];   // coalesced chunk prefetch
        int j = 0;
        for (; j + 2 <= cnt; j += 2) {
            int x0 = __shfl(mrec.x, j),     y0 = __shfl(mrec.y, j),     z0 = __shfl(mrec.z, j);
            int x1 = __shfl(mrec.x, j + 1), y1 = __shfl(mrec.y, j + 1), z1 = __shfl(mrec.z, j + 1);
            unsigned int u0 = tg[(size_t)y0 * 64 + lane];
            unsigned int u1 = tg[(size_t)y1 * 64 + lane];
            uint4 q0 = *(const uint4*)(xgg + ((size_t)x0 * 64 + lane) * 8);
            uint4 q1 = *(const uint4*)(xgg + ((size_t)x1 * 64 + lane) * 8);
            float lo0 = __uint_as_float(u0 << 16);
            float hi0 = __uint_as_float(u0 & 0xFFFF0000u);
            float lo1 = __uint_as_float(u1 << 16);
            float hi1 = __uint_as_float(u1 & 0xFFFF0000u);
            float wl0 = fmaf(__int_as_float(z0), hi0 - lo0, lo0);
            float wl1 = fmaf(__int_as_float(z1), hi1 - lo1, lo1);
            acc[0] = fmaf(__uint_as_float(q0.x << 16),         wl0, acc[0]);
            acc[1] = fmaf(__uint_as_float(q0.x & 0xFFFF0000u), wl0, acc[1]);
            acc[2] = fmaf(__uint_as_float(q0.y << 16),         wl0, acc[2]);
            acc[3] = fmaf(__uint_as_float(q0.y & 0xFFFF0000u), wl0, acc[3]);
            acc[4] = fmaf(__uint_as_float(q0.z << 16),         wl0, acc[4]);
            acc[5] = fmaf(__uint_as_float(q0.z & 0xFFFF0000u), wl0, acc[5]);
            acc[6] = fmaf(__uint_as_float(q0.w << 16),         wl0, acc[6]);
            acc[7] = fmaf(__uint_as_float(q0.w & 0xFFFF0000u), wl0, acc[7]);
            acc[0] = fmaf(__uint_as_float(q1.x << 16),         wl1, acc[0]);
            acc[1] = fmaf(__uint_as_float(q1.x & 0xFFFF0000u), wl1, acc[1]);
            acc[2] = fmaf(__uint_as_float(q1.y << 16),         wl1, acc[2]);
            acc[3] = fmaf(__uint_as_float(q1.y & 0xFFFF0000u), wl1, acc[3]);
            acc[4] = fmaf(__uint_as_float(q1.z << 16),         wl1, acc[4]);
            acc[5] = fmaf(__uint_as_float(q1.z & 0xFFFF0000u), wl1, acc[5]);
            acc[6] = fmaf(__uint_as_float(q1.w << 16),         wl1, acc[6]);
            acc[7] = fmaf(__uint_as_float(q1.w & 0xFFFF0000u), wl1, acc[7]);
        }
        if (j < cnt) {
            int x0 = __shfl(mrec.x, j), y0 = __shfl(mrec.y, j), z0 = __shfl(mrec.z, j);
            unsigned int u0 = tg[(size_t)y0 * 64 + lane];
            uint4 q = *(const uint4*)(xgg + ((size_t)x0 * 64 + lane) * 8);
            float lo0 = __uint_as_float(u0 << 16);
            float hi0 = __uint_as_float(u0 & 0xFFFF0000u);
            float wl = fmaf(__int_as_float(z0), hi0 - lo0, lo0);
            acc[0] = fmaf(__uint_as_float(q.x << 16),         wl, acc[0]);
            acc[1] = fmaf(__uint_as_float(q.x & 0xFFFF0000u), wl, acc[1]);
            acc[2] = fmaf(__uint_as_float(q.y << 16),         wl, acc[2]);
            acc[3] = fmaf(__uint_as_float(q.y & 0xFFFF0000u), wl, acc[3]);
            acc[4] = fmaf(__uint_as_float(q.z << 16),         wl, acc[4]);
            acc[5] = fmaf(__uint_as_float(q.z & 0xFFFF0000u), wl, acc[5]);
            acc[6] = fmaf(__uint_as_float(q.w << 16),         wl, acc[6]);
            acc[7] = fmaf(__uint_as_float(q.w & 0xFFFF0000u), wl, acc[7]);
        }
        i += cnt;
    }
    #pragma unroll
    for (int b2 = 0; b2 < 8; b2++) As[wv * 8 + b2][lane] = acc[b2];
    __syncthreads();                       // As gathered + Bs(cw2) staged

    int cg = t & 15, rg = t >> 4;
    int cc0 = cg * 4, r0 = rg * 2;
    float4 bias = *(const float4*)(conv_b2 + pb * 64 + cc0);
    float a0[4] = {bias.x, bias.y, bias.z, bias.w};
    float a1[4] = {bias.x, bias.y, bias.z, bias.w};
    gemm_tile(As, Bs, r0, cc0, a0, a1);
    __syncthreads();                       // gemm1 reads of As/Bs done
    *(float4*)&As[r0][cc0] =
        make_float4(sspf(a0[0]), sspf(a0[1]), sspf(a0[2]), sspf(a0[3]));
    *(float4*)&As[r0 + 1][cc0] =
        make_float4(sspf(a1[0]), sspf(a1[1]), sspf(a1[2]), sspf(a1[3]));
    stage_B(blk_w + pb * 4096, Bs, t);     // overwrite Bs (reads drained)
    __syncthreads();                       // As=ssp + Bs=blk_w ready
    float4 bb = *(const float4*)(blk_b + pb * 64 + cc0);
    float b0[4] = {bb.x, bb.y, bb.z, bb.w};
    float b1[4] = {bb.x, bb.y, bb.z, bb.w};
    gemm_tile(As, Bs, r0, cc0, b0, b1);
    int dstR = perm[pbase + gi * 4 + (r0 >> 3)];
    float* dp0 = dg + ((size_t)g * NN + (size_t)(r0 & 7) * AT + dstR) * 64 + cc0;
    float* dp1 = dg + ((size_t)g * NN + (size_t)((r0 + 1) & 7) * AT + dstR) * 64 + cc0;
    *(float4*)dp0 = make_float4(b0[0], b0[1], b0[2], b0[3]);
    *(float4*)dp1 = make_float4(b1[0], b1[1], b1[2], b1[3]);
}

// Fused h-update + next-layer lin1. Non-last grid = LTOT (candidate src
// tiles; h' written by g0 for site tiles, g2 for pore tiles). Last: grid MT,
// h'-update only. cv rows precomputed in cvbuf — direct L2-hot loads.
__global__ __launch_bounds__(256) void k_lin1f(
    const float* __restrict__ hIn, float* __restrict__ hOut,
    const float* __restrict__ dg, const float* __restrict__ conv_w1,
    const float* __restrict__ cvbuf,
    unsigned short* __restrict__ xg, int lcur, int last) {
    __shared__ float As[TILE_M][68];
    __shared__ float Bs[64][68];
    int t = threadIdx.x;
    int g, igrp;
    if (last) { g = 0; igrp = blockIdx.x; }
    else      lin1_map(blockIdx.x, g, igrp);
    int i0 = igrp * 4;
    int writeH = last ? 1 : (g != 1);
    const float* cvl = cvbuf + (size_t)lcur * 3 * 64;
    #pragma unroll
    for (int it = 0; it < 2; it++) {
        int v = t + it * 256;
        int r = v >> 4, c4 = (v & 15) * 4;
        int k = r >> 3, b = r & 7;
        int node_i = i0 + k;
        size_t o = ((size_t)b * AT + node_i) * 64 + c4;
        float4 hv = *(const float4*)(hIn + o);
        if (node_i < M1) {
            float4 d0 = *(const float4*)(dg + o);
            float4 d2 = *(const float4*)(dg + (size_t)2 * NN * 64 + o);
            float4 c1v = *(const float4*)(cvl + 64 + c4);
            hv.x += d0.x + c1v.x + d2.x;
            hv.y += d0.y + c1v.y + d2.y;
            hv.z += d0.z + c1v.z + d2.z;
            hv.w += d0.w + c1v.w + d2.w;
        } else {
            float4 d1 = *(const float4*)(dg + (size_t)NN * 64 + o);
            float4 c0v = *(const float4*)(cvl + c4);
            float4 c2v = *(const float4*)(cvl + 128 + c4);
            hv.x += c0v.x + d1.x + c2v.x;
            hv.y += c0v.y + d1.y + c2v.y;
            hv.z += c0v.z + d1.z + c2v.z;
            hv.w += c0v.w + d1.w + c2v.w;
        }
        *(float4*)&As[r][c4] = hv;
        if (writeH) *(float4*)(hOut + o) = hv;
    }
    if (last) return;
    stage_B(conv_w1 + (size_t)((lcur + 1) * 3 + g) * 4096, Bs, t);
    __syncthreads();
    int cg = t & 15, rg = t >> 4;
    int c0 = cg * 4, r0 = rg * 2;
    float acc0[4] = {0, 0, 0, 0}, acc1[4] = {0, 0, 0, 0};
    gemm_tile(As, Bs, r0, c0, acc0, acc1);
    __syncthreads();
    *(float4*)&As[r0][c0]     = make_float4(acc0[0], acc0[1], acc0[2], acc0[3]);
    *(float4*)&As[r0 + 1][c0] = make_float4(acc1[0], acc1[1], acc1[2], acc1[3]);
    __syncthreads();
    xg_transpose_store(As, xg, g, i0, t);
}

// Readout
__global__ void k_read(const float* __restrict__ h,
                       const float* __restrict__ w1, const float* __restrict__ b1,
                       const float* __restrict__ w2, const float* __restrict__ b2,
                       float* __restrict__ out) {
    int b = blockIdx.x;
    int lane = threadIdx.x & 63;
    int wv = threadIdx.x >> 6;
    __shared__ float part[4];
    float weff = 0.0f;
    #pragma unroll
    for (int j = 0; j < H / 2; j++) weff = fmaf(w1[lane * (H / 2) + j], w2[j], weff);
    float acc = 0.0f;
    for (int i = wv * (M2 / 4); i < (wv + 1) * (M2 / 4); i++)
        acc += h[((size_t)b * AT + M1 + i) * H + lane];
    float v = acc * weff;
    for (int off = 32; off; off >>= 1) v += __shfl_xor(v, off);
    if (lane == 0) part[wv] = v;
    __syncthreads();
    if (threadIdx.x == 0) {
        float bias = b2[0];
        for (int j = 0; j < H / 2; j++) bias = fmaf(b1[j], w2[j], bias);
        out[b] = part[0] + part[1] + part[2] + part[3] + (float)M2 * bias;
    }
}

// ---------------- launcher ----------------
extern "C" void kernel_launch(void* const* d_in, const int* in_sizes, int n_in,
                              void* d_out, int out_size, void* d_ws, size_t ws_size,
                              hipStream_t stream) {
    const int* sites   = (const int*)d_in[0];
    const int* sites_p = (const int*)d_in[1];
    const int* ei1 = (const int*)d_in[2];
    const float* ew1 = (const float*)d_in[3];
    const int* c1 = (const int*)d_in[4];
    const int* ei2 = (const int*)d_in[5];
    const float* ew2 = (const float*)d_in[6];
    const int* c2 = (const int*)d_in[7];
    const int* ei3 = (const int*)d_in[8];
    const float* ew3 = (const float*)d_in[9];
    const int* c3 = (const int*)d_in[10];
    const float* emb_w   = (const float*)d_in[11];
    const float* emb_p_w = (const float*)d_in[12];
    const float* mlp_w1 = (const float*)d_in[13];
    const float* mlp_b1 = (const float*)d_in[14];
    const float* mlp_w2 = (const float*)d_in[15];
    const float* mlp_b2 = (const float*)d_in[16];
    const float* conv_w1 = (const float*)d_in[17];
    const float* conv_w2 = (const float*)d_in[18];
    const float* conv_b2 = (const float*)d_in[19];
    const float* blk_w = (const float*)d_in[20];
    const float* blk_b = (const float*)d_in[21];
    const float* out_w1 = (const float*)d_in[22];
    const float* out_b1 = (const float*)d_in[23];
    const float* out_w2 = (const float*)d_in[24];
    const float* out_b2 = (const float*)d_in[25];

    char* ws = (char*)d_ws;
    float* hA   = (float*)(ws + O_HA);
    float* hB   = (float*)(ws + O_HB);
    unsigned short* xg = (unsigned short*)(ws + O_XG);
    float* dg   = (float*)(ws + O_DG);     // tabF aliases this before layer 0
    unsigned int* tab2 = (unsigned int*)(ws + O_TAB2);
    int4*  edata = (int4*)(ws + O_EDATA);
    int* ip    = (int*)(ws + O_INT);
    int* deg   = ip + I_DEG;
    int* cur   = ip + I_CUR;
    int* ibase = ip + I_BASE;
    int* dperm = ip + I_PERM;
    float* cvbuf = (float*)(ip + I_CV);

    hipMemsetAsync(ip, 0, (size_t)I_ZEND * sizeof(int), stream);

    k_setupA<<<A_TOT, 256, 0, stream>>>(mlp_w1, mlp_b1, mlp_w2, mlp_b2, dg,
                                        sites, sites_p, emb_w, emb_p_w, hA,
                                        ei1, ei2, ei3, c1, c2, c3, deg,
                                        conv_b2, blk_w, blk_b, cvbuf);
    k_setupB<<<B_TOT, 256, 0, stream>>>(dg, tab2, deg, ibase, dperm);
    k_fill<<<NBLK, 256, 0, stream>>>(ei1, ei2, ei3, c1, c2, c3, ew1, ew2, ew3,
                                     ibase, cur, edata);

    k_lin1t<<<LTOT, 256, 0, stream>>>(hA, conv_w1, xg, 0);
    float* hcur = hA;
    float* hnxt = hB;
    for (int l = 0; l < L; l++) {
        int last = (l == L - 1) ? 1 : 0;
        k_aggl<<<NBTOT, 256, 0, stream>>>(edata, ibase, dperm, xg, tab2,
                                          conv_w2, conv_b2, blk_w, blk_b,
                                          dg, l);
        k_lin1f<<<last ? MT : LTOT, 256, 0, stream>>>(hcur, hnxt, dg, conv_w1,
                                                      cvbuf, xg, l, last);
        float* tmp = hcur; hcur = hnxt; hnxt = tmp;
    }
    k_read<<<BS, 256, 0, stream>>>(hcur, out_w1, out_b1, out_w2, out_b2, (float*)d_out);
}